// Round 2
// baseline (37311.996 us; speedup 1.0000x reference)
//
#include <hip/hip_runtime.h>
#include <math.h>

typedef float f4 __attribute__((ext_vector_type(4)));
typedef float f2 __attribute__((ext_vector_type(2)));

constexpr int B_ = 4, C_ = 96, T_ = 320, F_ = 256;
constexpr int TF_ = T_ * F_;          // 81920
constexpr float EPS_ = 1e-5f;

// ---------------------------------------------------------------------------
// 1x1 conv (pointwise GEMM over channels) + BatchNorm(inference) + PReLU.
// x: (G, CIN, P)  W: (COUT, CIN)  y: (G, COUT, P)
// 64-thread blocks (1 wave) for even CU load balance on per-b grids.
// ---------------------------------------------------------------------------
template<int CIN, int COUT>
__global__ __launch_bounds__(64)
void conv_bn_prelu(const float* __restrict__ x, const float* __restrict__ W,
                   const float* __restrict__ bias, const float* __restrict__ gamma,
                   const float* __restrict__ beta, const float* __restrict__ mean,
                   const float* __restrict__ var,  const float* __restrict__ aP,
                   float* __restrict__ y, int P, int blocksPerG)
{
    const int g = blockIdx.x / blocksPerG;
    const int p = (blockIdx.x % blocksPerG) * 64 + threadIdx.x;
    if (p >= P) return;
    const float a = aP[0];
    const float* xg = x + (size_t)g * CIN * P + p;
    float xv[CIN];
#pragma unroll
    for (int c = 0; c < CIN; ++c) xv[c] = xg[(size_t)c * P];
    float* yg = y + (size_t)g * COUT * P + p;
    for (int o = 0; o < COUT; ++o) {
        const float* w = W + o * CIN;
        float a0 = 0.f, a1 = 0.f, a2 = 0.f, a3 = 0.f;   // 4 partials for ILP
#pragma unroll
        for (int c = 0; c < CIN; c += 4) {
            a0 = fmaf(w[c + 0], xv[c + 0], a0);
            a1 = fmaf(w[c + 1], xv[c + 1], a1);
            a2 = fmaf(w[c + 2], xv[c + 2], a2);
            a3 = fmaf(w[c + 3], xv[c + 3], a3);
        }
        const float acc = (a0 + a1) + (a2 + a3);
        const float sc = gamma[o] * rsqrtf(var[o] + EPS_);
        const float v  = fmaf(acc, sc, fmaf(bias[o] - mean[o], sc, beta[o]));
        yg[(size_t)o * P] = v >= 0.f ? v : a * v;
    }
}

// ---------------------------------------------------------------------------
// 2D transpose with optional residual add (single batch).
// out[m][n] = in[n][m] (+ res[m][n]);  in: (No, Mo)  out: (Mo, No)
// ---------------------------------------------------------------------------
__global__ __launch_bounds__(256)
void transpose_res(const float* __restrict__ in, const float* __restrict__ res,
                   float* __restrict__ out, int Mo, int No)
{
    __shared__ float tile[32][33];
    const int n0 = blockIdx.x * 32, m0 = blockIdx.y * 32;
    const int tx = threadIdx.x, ty = threadIdx.y;
#pragma unroll
    for (int i = 0; i < 32; i += 8)
        tile[ty + i][tx] = in[(size_t)(n0 + ty + i) * Mo + (m0 + tx)];
    __syncthreads();
#pragma unroll
    for (int i = 0; i < 32; i += 8) {
        const size_t oidx = (size_t)(m0 + ty + i) * No + (n0 + tx);
        float v = tile[tx][ty + i];
        if (res) v += res[oidx];
        out[oidx] = v;
    }
}

// ---------------------------------------------------------------------------
// Fused attention (single batch): S = softmax(Q^T K / sqrt(C)); O = V @ P^T
// MODE 0 (f-attn): groups t in [0,320), NY=256, channel stride TF_
// MODE 1 (t-attn): groups f in [0,256), NY=320, channel stride T_
// Block = one 64-row strip of S. LDS: A region (Q strip -> V tiles),
// B region (K -> P). Per-thread 4 rows x NJ cols, chunk-rotated reads.
// ---------------------------------------------------------------------------
template<int MODE>
__global__ __launch_bounds__(256)
void attn_kernel(const float* __restrict__ Qb, const float* __restrict__ Kb,
                 const float* __restrict__ Vb, float* __restrict__ Ob)
{
    constexpr int NY   = (MODE == 0) ? 256 : 320;
    constexpr int LD   = (MODE == 0) ? TF_ : T_;
    constexpr int NJ   = NY / 16;          // per-thread y count (16 / 20)
    constexpr int NC4  = NJ / 4;           // float4 chunks (4 / 5)
    constexpr int PPAD = NY + 4;           // 260 / 324 (16B-aligned rows)
    constexpr int SPG  = (MODE == 0) ? (F_ / 64) : (T_ / 64);
    constexpr int GOFF = (MODE == 0) ? F_ : C_ * T_;   // per-group offset

    extern __shared__ float lds[];
    float* Alds = lds;            // Q strip [96][64] then V tile [64][100]
    float* Blds = lds + 6400;     // K [96][NY]      then P [64][PPAD]

    const int strip = blockIdx.x % SPG;
    const int grp   = blockIdx.x / SPG;
    const int m0    = strip * 64;
    const size_t off = (size_t)grp * GOFF;
    const float* Q = Qb + off;
    const float* K = Kb + off;
    const float* V = Vb + off;
    float*       O = Ob + off;

    const int tid = threadIdx.x;
    // ---- stage Q strip and full K ----
    for (int e = tid; e < 96 * 64; e += 256) {
        const int kk = e >> 6, mm = e & 63;
        Alds[kk * 64 + mm] = Q[(size_t)kk * LD + m0 + mm];
    }
    for (int e = tid; e < 96 * NY; e += 256) {
        const int kk = e / NY, nn = e - kk * NY;
        Blds[kk * NY + nn] = K[(size_t)kk * LD + nn];
    }
    __syncthreads();

    // ---- S = Q^T K (4 rows x NJ cols per thread) ----
    const int ty = tid >> 4, tx = tid & 15;
    const int rotbase = (NC4 == 4) ? ((tx >> 1) & 3) : (tx % 5);
    float s[4][NJ];
#pragma unroll
    for (int i = 0; i < 4; ++i)
#pragma unroll
        for (int j = 0; j < NJ; ++j) s[i][j] = 0.f;

    for (int kk = 0; kk < 96; ++kk) {
        const f4 qv = *(const f4*)&Alds[kk * 64 + ty * 4];
#pragma unroll
        for (int c4 = 0; c4 < NC4; ++c4) {
            int cc = rotbase + c4; if (cc >= NC4) cc -= NC4;    // bank-stagger
            const f4 kv = *(const f4*)&Blds[kk * NY + tx * NJ + cc * 4];
#pragma unroll
            for (int i = 0; i < 4; ++i) {
#pragma unroll
                for (int j = 0; j < 4; ++j)
                    s[i][cc * 4 + j] = fmaf(qv[i], kv[j], s[i][cc * 4 + j]);
            }
        }
    }
    __syncthreads();    // all K reads done; B region may be reused for P

    // ---- softmax over rows (16 lanes per row) ----
    const float scale = 0.10206207261596575f;   // 1/sqrt(96)
#pragma unroll
    for (int i = 0; i < 4; ++i) {
#pragma unroll
        for (int j = 0; j < NJ; ++j) s[i][j] *= scale;
        float m = s[i][0];
#pragma unroll
        for (int j = 1; j < NJ; ++j) m = fmaxf(m, s[i][j]);
        for (int d = 1; d < 16; d <<= 1) m = fmaxf(m, __shfl_xor(m, d));
        float l = 0.f;
#pragma unroll
        for (int j = 0; j < NJ; ++j) { s[i][j] = __expf(s[i][j] - m); l += s[i][j]; }
        for (int d = 1; d < 16; d <<= 1) l += __shfl_xor(l, d);
        const float inv = 1.f / l;
#pragma unroll
        for (int j = 0; j < NJ; ++j) s[i][j] *= inv;
    }
    // ---- write P (row-major [64][PPAD]) into B region ----
#pragma unroll
    for (int i = 0; i < 4; ++i) {
#pragma unroll
        for (int c4 = 0; c4 < NC4; ++c4) {
            int cc = rotbase + c4; if (cc >= NC4) cc -= NC4;
            f4 w; w[0] = s[i][cc*4]; w[1] = s[i][cc*4+1]; w[2] = s[i][cc*4+2]; w[3] = s[i][cc*4+3];
            *(f4*)&Blds[(ty * 4 + i) * PPAD + tx * NJ + cc * 4] = w;
        }
    }

    // ---- O_strip = V @ P^T, streaming V in 64-wide y tiles ----
    const int cg = tid & 7, fg = tid >> 3;   // c0 = 12*cg, rows m = 2*fg,2*fg+1
    float accA[12], accB[12];
#pragma unroll
    for (int i = 0; i < 12; ++i) { accA[i] = 0.f; accB[i] = 0.f; }

    for (int yt = 0; yt < NY / 64; ++yt) {
        __syncthreads();
        for (int e = tid; e < 96 * 64; e += 256) {      // V tile, transposed store
            const int cI = e >> 6, yI = e & 63;
            Alds[yI * 100 + cI] = V[(size_t)cI * LD + yt * 64 + yI];
        }
        __syncthreads();
        const float* Prow0 = &Blds[(2 * fg) * PPAD + yt * 64];
        const float* Prow1 = Prow0 + PPAD;
        for (int y = 0; y < 64; ++y) {
            const f4 va = *(const f4*)&Alds[y * 100 + cg * 12];
            const f4 vb = *(const f4*)&Alds[y * 100 + cg * 12 + 4];
            const f4 vc = *(const f4*)&Alds[y * 100 + cg * 12 + 8];
            const float p0 = Prow0[y], p1 = Prow1[y];
#pragma unroll
            for (int i = 0; i < 4; ++i) {
                accA[i]     = fmaf(va[i], p0, accA[i]);
                accB[i]     = fmaf(va[i], p1, accB[i]);
                accA[4 + i] = fmaf(vb[i], p0, accA[4 + i]);
                accB[4 + i] = fmaf(vb[i], p1, accB[4 + i]);
                accA[8 + i] = fmaf(vc[i], p0, accA[8 + i]);
                accB[8 + i] = fmaf(vc[i], p1, accB[8 + i]);
            }
        }
    }
#pragma unroll
    for (int i = 0; i < 12; ++i) {
        f2 w; w[0] = accA[i]; w[1] = accB[i];
        *(f2*)&O[(size_t)(cg * 12 + i) * LD + m0 + 2 * fg] = w;
    }
}

// ---------------------------------------------------------------------------
extern "C" void kernel_launch(void* const* d_in, const int* in_sizes, int n_in,
                              void* d_out, int out_size, void* d_ws, size_t ws_size,
                              hipStream_t stream)
{
    const float* inp = (const float*)d_in[0];
    const float* W_f = (const float*)d_in[1];  const float* b_f = (const float*)d_in[2];
    const float* g_f = (const float*)d_in[3];  const float* be_f = (const float*)d_in[4];
    const float* m_f = (const float*)d_in[5];  const float* v_f = (const float*)d_in[6];
    const float* a_f = (const float*)d_in[7];
    const float* W_t = (const float*)d_in[8];  const float* b_t = (const float*)d_in[9];
    const float* g_t = (const float*)d_in[10]; const float* be_t = (const float*)d_in[11];
    const float* m_t = (const float*)d_in[12]; const float* v_t = (const float*)d_in[13];
    const float* a_t = (const float*)d_in[14];
    const float* W_p = (const float*)d_in[15]; const float* b_p = (const float*)d_in[16];
    const float* g_p = (const float*)d_in[17]; const float* be_p = (const float*)d_in[18];
    const float* m_p = (const float*)d_in[19]; const float* v_p = (const float*)d_in[20];
    const float* a_p = (const float*)d_in[21];

    hipFuncSetAttribute((const void*)attn_kernel<0>,
                        hipFuncAttributeMaxDynamicSharedMemorySize, 123904);
    hipFuncSetAttribute((const void*)attn_kernel<1>,
                        hipFuncAttributeMaxDynamicSharedMemorySize, 148480);

    // Per-batch pipeline. ws peak = 3 quarter-buffers = 23,592,960 floats
    // (94.4 MB). d_out's batch slice doubles as scratch (fout, then tkT).
    constexpr size_t QH  = (size_t)C_ * T_ * F_;   // 7,864,320 floats (31.5 MB)
    constexpr size_t CTF = QH;                      // per-batch slice of inp/out
    float* ws = (float*)d_ws;

    for (int b = 0; b < B_; ++b) {
        const float* xb   = inp + (size_t)b * CTF;
        float*       dob  = (float*)d_out + (size_t)b * CTF;
        float* fqkv  = ws;            // [0, 3*QH)     L1 -> L2
        float* foutT = ws;            // [0, QH)       L3 -> t-attn (fqkv dead)
        float* th    = ws + QH;       // [QH, 2*QH)    conv_t half out (twice)
        float* tqT   = ws + 2 * QH;   // [2*QH, 3*QH)  L5 -> t-attn
        float* tout  = ws + QH;       // over dead th
        float* tmp   = ws + 2 * QH;   // over dead tqT

        // 1. f_qkv = cbp(inp_b, W_f)            (3C, T, F)
        conv_bn_prelu<96, 288><<<dim3(1280), dim3(64), 0, stream>>>(
            xb, W_f, b_f, g_f, be_f, m_f, v_f, a_f, fqkv, TF_, 1280);
        // 2. f-attention -> fout in d_out slice (C, T, F)
        attn_kernel<0><<<dim3(T_ * (F_ / 64)), dim3(256), 123904, stream>>>(
            fqkv, fqkv + (size_t)C_ * TF_, fqkv + (size_t)2 * C_ * TF_, dob);
        // 3. foutT = transpose(fout)            (F, C, T)
        transpose_res<<<dim3(960, 8, 1), dim3(32, 8), 0, stream>>>(
            dob, nullptr, foutT, F_, C_ * T_);
        // 4a. conv_t q-half -> th               (C, T, F)
        conv_bn_prelu<96, 96><<<dim3(1280), dim3(64), 0, stream>>>(
            xb, W_t, b_t, g_t, be_t, m_t, v_t, a_t, th, TF_, 1280);
        // 4b. tqT = transpose(th)               (F, C, T)
        transpose_res<<<dim3(960, 8, 1), dim3(32, 8), 0, stream>>>(
            th, nullptr, tqT, F_, C_ * T_);
        // 5a. conv_t k-half -> th
        conv_bn_prelu<96, 96><<<dim3(1280), dim3(64), 0, stream>>>(
            xb, W_t + 96 * 96, b_t + 96, g_t + 96, be_t + 96, m_t + 96, v_t + 96,
            a_t, th, TF_, 1280);
        // 5b. tkT = transpose(th) -> d_out slice (fout is dead now)
        transpose_res<<<dim3(960, 8, 1), dim3(32, 8), 0, stream>>>(
            th, nullptr, dob, F_, C_ * T_);
        // 6. t-attention -> tout                (F, C, T)
        attn_kernel<1><<<dim3(F_ * (T_ / 64)), dim3(256), 148480, stream>>>(
            tqT, dob, foutT, tout);
        // 7. conv_p over groups f -> tmp        (F, C, T)
        conv_bn_prelu<96, 96><<<dim3(F_ * 5), dim3(64), 0, stream>>>(
            tout, W_p, b_p, g_p, be_p, m_p, v_p, a_p, tmp, T_, 5);
        // 8. out_b = transpose(tmp) + inp_b     (C, T, F)  (overwrites tkT)
        transpose_res<<<dim3(8, 960, 1), dim3(32, 8), 0, stream>>>(
            tmp, xb, dob, C_ * T_, F_);
    }
}

// Round 3
// 3907.448 us; speedup vs baseline: 9.5489x; 9.5489x over previous
//
#include <hip/hip_runtime.h>
#include <math.h>

typedef float f4 __attribute__((ext_vector_type(4)));
typedef float f2 __attribute__((ext_vector_type(2)));

constexpr int B_ = 4, C_ = 96, T_ = 320, F_ = 256;
constexpr int TF_ = T_ * F_;          // 81920
constexpr float EPS_ = 1e-5f;

// ---------------------------------------------------------------------------
// 1x1 conv (pointwise GEMM over channels) + BatchNorm(inference) + PReLU.
// x: (G, CIN, P)  W: (COUT, CIN)  y: (G, COUT, P)
// ---------------------------------------------------------------------------
template<int CIN, int COUT>
__global__ __launch_bounds__(64)
void conv_bn_prelu(const float* __restrict__ x, const float* __restrict__ W,
                   const float* __restrict__ bias, const float* __restrict__ gamma,
                   const float* __restrict__ beta, const float* __restrict__ mean,
                   const float* __restrict__ var,  const float* __restrict__ aP,
                   float* __restrict__ y, int P, int blocksPerG)
{
    const int g = blockIdx.x / blocksPerG;
    const int p = (blockIdx.x % blocksPerG) * 64 + threadIdx.x;
    if (p >= P) return;
    const float a = aP[0];
    const float* xg = x + (size_t)g * CIN * P + p;
    float xv[CIN];
#pragma unroll
    for (int c = 0; c < CIN; ++c) xv[c] = xg[(size_t)c * P];
    float* yg = y + (size_t)g * COUT * P + p;
    for (int o = 0; o < COUT; ++o) {
        const float* w = W + o * CIN;
        float a0 = 0.f, a1 = 0.f, a2 = 0.f, a3 = 0.f;   // 4 partials for ILP
#pragma unroll
        for (int c = 0; c < CIN; c += 4) {
            a0 = fmaf(w[c + 0], xv[c + 0], a0);
            a1 = fmaf(w[c + 1], xv[c + 1], a1);
            a2 = fmaf(w[c + 2], xv[c + 2], a2);
            a3 = fmaf(w[c + 3], xv[c + 3], a3);
        }
        const float acc = (a0 + a1) + (a2 + a3);
        const float sc = gamma[o] * rsqrtf(var[o] + EPS_);
        const float v  = fmaf(acc, sc, fmaf(bias[o] - mean[o], sc, beta[o]));
        yg[(size_t)o * P] = v >= 0.f ? v : a * v;
    }
}

// ---------------------------------------------------------------------------
// 2D transpose with optional residual add (single batch).
// out[m][n] = in[n][m] (+ res[m][n]);  in: (No, Mo)  out: (Mo, No)
// ---------------------------------------------------------------------------
__global__ __launch_bounds__(256)
void transpose_res(const float* __restrict__ in, const float* __restrict__ res,
                   float* __restrict__ out, int Mo, int No)
{
    __shared__ float tile[32][33];
    const int n0 = blockIdx.x * 32, m0 = blockIdx.y * 32;
    const int tx = threadIdx.x, ty = threadIdx.y;
#pragma unroll
    for (int i = 0; i < 32; i += 8)
        tile[ty + i][tx] = in[(size_t)(n0 + ty + i) * Mo + (m0 + tx)];
    __syncthreads();
#pragma unroll
    for (int i = 0; i < 32; i += 8) {
        const size_t oidx = (size_t)(m0 + ty + i) * No + (n0 + tx);
        float v = tile[tx][ty + i];
        if (res) v += res[oidx];
        out[oidx] = v;
    }
}

// ---------------------------------------------------------------------------
// Fused attention (single batch): S = softmax(Q^T K / sqrt(C)); O = V @ P^T
// MODE 0 (f-attn): groups t in [0,320), NY=256, channel stride TF_
// MODE 1 (t-attn): groups f in [0,256), NY=320, channel stride T_
// Block = one 64-row strip of S.
// Column ownership: thread tx owns columns {c4*64 + tx*4 + j} (interleaved
// chunks) -> LDS reads span exactly 2 bank rows (2-way = free) AND the
// accumulator index is compile-time (no scratch demotion — round-2 lesson).
// ---------------------------------------------------------------------------
template<int MODE>
__global__ __launch_bounds__(256)
void attn_kernel(const float* __restrict__ Qb, const float* __restrict__ Kb,
                 const float* __restrict__ Vb, float* __restrict__ Ob)
{
    constexpr int NY   = (MODE == 0) ? 256 : 320;
    constexpr int LD   = (MODE == 0) ? TF_ : T_;
    constexpr int NJ   = NY / 16;          // per-thread y count (16 / 20)
    constexpr int NC4  = NJ / 4;           // float4 chunks (4 / 5)
    constexpr int PPAD = NY + 4;           // 260 / 324 (16B-aligned rows)
    constexpr int SPG  = (MODE == 0) ? (F_ / 64) : (T_ / 64);
    constexpr int GOFF = (MODE == 0) ? F_ : C_ * T_;   // per-group offset

    extern __shared__ float lds[];
    float* Alds = lds;            // Q strip [96][64] then V tile [64][100]
    float* Blds = lds + 6400;     // K [96][NY]      then P [64][PPAD]

    const int strip = blockIdx.x % SPG;
    const int grp   = blockIdx.x / SPG;
    const int m0    = strip * 64;
    const size_t off = (size_t)grp * GOFF;
    const float* Q = Qb + off;
    const float* K = Kb + off;
    const float* V = Vb + off;
    float*       O = Ob + off;

    const int tid = threadIdx.x;
    // ---- stage Q strip and full K ----
    for (int e = tid; e < 96 * 64; e += 256) {
        const int kk = e >> 6, mm = e & 63;
        Alds[kk * 64 + mm] = Q[(size_t)kk * LD + m0 + mm];
    }
    for (int e = tid; e < 96 * NY; e += 256) {
        const int kk = e / NY, nn = e - kk * NY;
        Blds[kk * NY + nn] = K[(size_t)kk * LD + nn];
    }
    __syncthreads();

    // ---- S = Q^T K (4 rows x NJ cols per thread) ----
    const int ty = tid >> 4, tx = tid & 15;
    float s[4][NJ];
#pragma unroll
    for (int i = 0; i < 4; ++i)
#pragma unroll
        for (int j = 0; j < NJ; ++j) s[i][j] = 0.f;

    for (int kk = 0; kk < 96; ++kk) {
        const f4 qv = *(const f4*)&Alds[kk * 64 + ty * 4];
#pragma unroll
        for (int c4 = 0; c4 < NC4; ++c4) {
            const f4 kv = *(const f4*)&Blds[kk * NY + c4 * 64 + tx * 4];
#pragma unroll
            for (int i = 0; i < 4; ++i) {
#pragma unroll
                for (int j = 0; j < 4; ++j)
                    s[i][c4 * 4 + j] = fmaf(qv[i], kv[j], s[i][c4 * 4 + j]);
            }
        }
    }
    __syncthreads();    // all K reads done; B region may be reused for P

    // ---- softmax over rows (16 lanes per row; column-permutation invariant) ----
    const float scale = 0.10206207261596575f;   // 1/sqrt(96)
#pragma unroll
    for (int i = 0; i < 4; ++i) {
#pragma unroll
        for (int j = 0; j < NJ; ++j) s[i][j] *= scale;
        float m = s[i][0];
#pragma unroll
        for (int j = 1; j < NJ; ++j) m = fmaxf(m, s[i][j]);
        for (int d = 1; d < 16; d <<= 1) m = fmaxf(m, __shfl_xor(m, d));
        float l = 0.f;
#pragma unroll
        for (int j = 0; j < NJ; ++j) { s[i][j] = __expf(s[i][j] - m); l += s[i][j]; }
        for (int d = 1; d < 16; d <<= 1) l += __shfl_xor(l, d);
        const float inv = 1.f / l;
#pragma unroll
        for (int j = 0; j < NJ; ++j) s[i][j] *= inv;
    }
    // ---- write P (row-major [64][PPAD]) into B region ----
#pragma unroll
    for (int i = 0; i < 4; ++i) {
#pragma unroll
        for (int c4 = 0; c4 < NC4; ++c4) {
            f4 w; w[0] = s[i][c4*4]; w[1] = s[i][c4*4+1];
                  w[2] = s[i][c4*4+2]; w[3] = s[i][c4*4+3];
            *(f4*)&Blds[(ty * 4 + i) * PPAD + c4 * 64 + tx * 4] = w;
        }
    }

    // ---- O_strip = V @ P^T, streaming V in 64-wide y tiles ----
    const int cg = tid & 7, fg = tid >> 3;   // c0 = 12*cg, rows m = 2*fg,2*fg+1
    float accA[12], accB[12];
#pragma unroll
    for (int i = 0; i < 12; ++i) { accA[i] = 0.f; accB[i] = 0.f; }

    for (int yt = 0; yt < NY / 64; ++yt) {
        __syncthreads();
        for (int e = tid; e < 96 * 64; e += 256) {      // V tile, transposed store
            const int cI = e >> 6, yI = e & 63;
            Alds[yI * 100 + cI] = V[(size_t)cI * LD + yt * 64 + yI];
        }
        __syncthreads();
        const float* Prow0 = &Blds[(2 * fg) * PPAD + yt * 64];
        const float* Prow1 = Prow0 + PPAD;
        for (int y = 0; y < 64; ++y) {
            const f4 va = *(const f4*)&Alds[y * 100 + cg * 12];
            const f4 vb = *(const f4*)&Alds[y * 100 + cg * 12 + 4];
            const f4 vc = *(const f4*)&Alds[y * 100 + cg * 12 + 8];
            const float p0 = Prow0[y], p1 = Prow1[y];
#pragma unroll
            for (int i = 0; i < 4; ++i) {
                accA[i]     = fmaf(va[i], p0, accA[i]);
                accB[i]     = fmaf(va[i], p1, accB[i]);
                accA[4 + i] = fmaf(vb[i], p0, accA[4 + i]);
                accB[4 + i] = fmaf(vb[i], p1, accB[4 + i]);
                accA[8 + i] = fmaf(vc[i], p0, accA[8 + i]);
                accB[8 + i] = fmaf(vc[i], p1, accB[8 + i]);
            }
        }
    }
#pragma unroll
    for (int i = 0; i < 12; ++i) {
        f2 w; w[0] = accA[i]; w[1] = accB[i];
        *(f2*)&O[(size_t)(cg * 12 + i) * LD + m0 + 2 * fg] = w;
    }
}

// ---------------------------------------------------------------------------
extern "C" void kernel_launch(void* const* d_in, const int* in_sizes, int n_in,
                              void* d_out, int out_size, void* d_ws, size_t ws_size,
                              hipStream_t stream)
{
    const float* inp = (const float*)d_in[0];
    const float* W_f = (const float*)d_in[1];  const float* b_f = (const float*)d_in[2];
    const float* g_f = (const float*)d_in[3];  const float* be_f = (const float*)d_in[4];
    const float* m_f = (const float*)d_in[5];  const float* v_f = (const float*)d_in[6];
    const float* a_f = (const float*)d_in[7];
    const float* W_t = (const float*)d_in[8];  const float* b_t = (const float*)d_in[9];
    const float* g_t = (const float*)d_in[10]; const float* be_t = (const float*)d_in[11];
    const float* m_t = (const float*)d_in[12]; const float* v_t = (const float*)d_in[13];
    const float* a_t = (const float*)d_in[14];
    const float* W_p = (const float*)d_in[15]; const float* b_p = (const float*)d_in[16];
    const float* g_p = (const float*)d_in[17]; const float* be_p = (const float*)d_in[18];
    const float* m_p = (const float*)d_in[19]; const float* v_p = (const float*)d_in[20];
    const float* a_p = (const float*)d_in[21];

    hipFuncSetAttribute((const void*)attn_kernel<0>,
                        hipFuncAttributeMaxDynamicSharedMemorySize, 123904);
    hipFuncSetAttribute((const void*)attn_kernel<1>,
                        hipFuncAttributeMaxDynamicSharedMemorySize, 148480);

    // Per-batch pipeline. ws peak = 3 quarter-buffers = 23,592,960 floats
    // (94.4 MB). d_out's batch slice doubles as scratch (fout, then tkT).
    constexpr size_t QH  = (size_t)C_ * T_ * F_;   // 7,864,320 floats (31.5 MB)
    constexpr size_t CTF = QH;                      // per-batch slice of inp/out
    float* ws = (float*)d_ws;

    for (int b = 0; b < B_; ++b) {
        const float* xb   = inp + (size_t)b * CTF;
        float*       dob  = (float*)d_out + (size_t)b * CTF;
        float* fqkv  = ws;            // [0, 3*QH)     L1 -> L2
        float* foutT = ws;            // [0, QH)       L3 -> t-attn (fqkv dead)
        float* th    = ws + QH;       // [QH, 2*QH)    conv_t half out (twice)
        float* tqT   = ws + 2 * QH;   // [2*QH, 3*QH)  L5 -> t-attn
        float* tout  = ws + QH;       // over dead th
        float* tmp   = ws + 2 * QH;   // over dead tqT

        // 1. f_qkv = cbp(inp_b, W_f)            (3C, T, F)
        conv_bn_prelu<96, 288><<<dim3(1280), dim3(64), 0, stream>>>(
            xb, W_f, b_f, g_f, be_f, m_f, v_f, a_f, fqkv, TF_, 1280);
        // 2. f-attention -> fout in d_out slice (C, T, F)
        attn_kernel<0><<<dim3(T_ * (F_ / 64)), dim3(256), 123904, stream>>>(
            fqkv, fqkv + (size_t)C_ * TF_, fqkv + (size_t)2 * C_ * TF_, dob);
        // 3. foutT = transpose(fout)            (F, C, T)
        transpose_res<<<dim3(960, 8, 1), dim3(32, 8), 0, stream>>>(
            dob, nullptr, foutT, F_, C_ * T_);
        // 4a. conv_t q-half -> th               (C, T, F)
        conv_bn_prelu<96, 96><<<dim3(1280), dim3(64), 0, stream>>>(
            xb, W_t, b_t, g_t, be_t, m_t, v_t, a_t, th, TF_, 1280);
        // 4b. tqT = transpose(th)               (F, C, T)
        transpose_res<<<dim3(960, 8, 1), dim3(32, 8), 0, stream>>>(
            th, nullptr, tqT, F_, C_ * T_);
        // 5a. conv_t k-half -> th
        conv_bn_prelu<96, 96><<<dim3(1280), dim3(64), 0, stream>>>(
            xb, W_t + 96 * 96, b_t + 96, g_t + 96, be_t + 96, m_t + 96, v_t + 96,
            a_t, th, TF_, 1280);
        // 5b. tkT = transpose(th) -> d_out slice (fout is dead now)
        transpose_res<<<dim3(960, 8, 1), dim3(32, 8), 0, stream>>>(
            th, nullptr, dob, F_, C_ * T_);
        // 6. t-attention -> tout                (F, C, T)
        attn_kernel<1><<<dim3(F_ * (T_ / 64)), dim3(256), 148480, stream>>>(
            tqT, dob, foutT, tout);
        // 7. conv_p over groups f -> tmp        (F, C, T)
        conv_bn_prelu<96, 96><<<dim3(F_ * 5), dim3(64), 0, stream>>>(
            tout, W_p, b_p, g_p, be_p, m_p, v_p, a_p, tmp, T_, 5);
        // 8. out_b = transpose(tmp) + inp_b     (C, T, F)  (overwrites tkT)
        transpose_res<<<dim3(8, 960, 1), dim3(32, 8), 0, stream>>>(
            tmp, xb, dob, C_ * T_, F_);
    }
}

// Round 4
// 3064.606 us; speedup vs baseline: 12.1751x; 1.2750x over previous
//
#include <hip/hip_runtime.h>
#include <math.h>

typedef float f4 __attribute__((ext_vector_type(4)));
typedef float f2 __attribute__((ext_vector_type(2)));

constexpr int B_ = 4, C_ = 96, T_ = 320, F_ = 256;
constexpr int TF_ = T_ * F_;          // 81920
constexpr float EPS_ = 1e-5f;

// ---------------------------------------------------------------------------
// Tiled 1x1-conv GEMM + BN + PReLU.  y[g][co][p] = act(BN(sum_k W[co][k] x[g][k][p]))
// Block: 256 threads, tile = 96 co x 160 p, K = 96 single-shot in LDS.
// Thread: 6 co x 10 p (60 accs, statically indexed).  p-set = two f4 chunks
// + one f2 chunk, all naturally aligned; LDS bank aliasing <= 2-way (free).
// LDS: Xs[96][160] (60 KB) + Wt[96][96] (36 KB) = 96 KB dynamic.
// ---------------------------------------------------------------------------
template<int COUT>
__global__ __launch_bounds__(256)
void conv_gemm(const float* __restrict__ x, const float* __restrict__ W,
               const float* __restrict__ bias, const float* __restrict__ gamma,
               const float* __restrict__ beta, const float* __restrict__ mean,
               const float* __restrict__ var,  const float* __restrict__ aP,
               float* __restrict__ y, int P, int ptilesPerG)
{
    constexpr int NCO = COUT / 96;
    extern __shared__ float lds[];
    float* Xs = lds;              // [96][160]
    float* Wt = lds + 96 * 160;   // [96 kk][96 co]

    const int tid = threadIdx.x;
    const int pt  = blockIdx.x % ptilesPerG;                  // p fastest: X tile
    const int cot = (blockIdx.x / ptilesPerG) % NCO;          //   shared via L3
    const int g   = blockIdx.x / (ptilesPerG * NCO);
    const int p0  = pt * 160;

    const float* xg = x + (size_t)g * 96 * P + p0;
    for (int e = tid; e < 96 * 40; e += 256) {                // X stage (f4)
        const int kk = e / 40, ch = e - kk * 40;
        *(f4*)&Xs[kk * 160 + ch * 4] = *(const f4*)&xg[(size_t)kk * P + ch * 4];
    }
    const float* wg = W + (size_t)cot * 96 * 96;
    for (int e = tid; e < 96 * 96; e += 256) {                // Wt stage:
        const int co = e % 96, kk = e / 96;                   // LDS conflict-free,
        Wt[kk * 96 + co] = wg[(size_t)co * 96 + kk];          // global L2-served
    }
    __syncthreads();

    const int cg = tid >> 4, pg = tid & 15;                   // 16 co-grp x 16 p-grp
    const float* xbase = Xs + pg * 4;                         // p = {pg*4+j, 64+pg*4+j, 128+pg*2+j2}
    const float* wbase = Wt + cg * 6;
    float acc[6][10];
#pragma unroll
    for (int i = 0; i < 6; ++i)
#pragma unroll
        for (int j = 0; j < 10; ++j) acc[i][j] = 0.f;

#pragma unroll 2
    for (int kk = 0; kk < 96; ++kk) {
        const float* xr = xbase + kk * 160;
        const float* wr = wbase + kk * 96;
        const f4 xA = *(const f4*)xr;                         // p0..p0+3
        const f4 xB = *(const f4*)(xr + 64);                  // 64+..
        const f2 xC = *(const f2*)(Xs + kk * 160 + 128 + pg * 2);
        const f2 wA = *(const f2*)wr;
        const f2 wB = *(const f2*)(wr + 2);
        const f2 wC = *(const f2*)(wr + 4);
        const float xv[10] = {xA[0],xA[1],xA[2],xA[3], xB[0],xB[1],xB[2],xB[3],
                              xC[0],xC[1]};
        const float wv[6]  = {wA[0],wA[1], wB[0],wB[1], wC[0],wC[1]};
#pragma unroll
        for (int i = 0; i < 6; ++i)
#pragma unroll
            for (int j = 0; j < 10; ++j)
                acc[i][j] = fmaf(wv[i], xv[j], acc[i][j]);
    }

    const float a = aP[0];
    const int coBase = cot * 96 + cg * 6;
#pragma unroll
    for (int i = 0; i < 6; ++i) {
        const int co = coBase + i;
        const float sc = gamma[co] * rsqrtf(var[co] + EPS_);
        const float sh = fmaf(bias[co] - mean[co], sc, beta[co]);
        float* yr = y + ((size_t)g * COUT + co) * P + p0;
        f4 o1, o2; f2 o3;
#pragma unroll
        for (int j = 0; j < 4; ++j) {
            float v = fmaf(acc[i][j], sc, sh);     o1[j] = v >= 0.f ? v : a * v;
            float w = fmaf(acc[i][4 + j], sc, sh); o2[j] = w >= 0.f ? w : a * w;
        }
#pragma unroll
        for (int j = 0; j < 2; ++j) {
            float v = fmaf(acc[i][8 + j], sc, sh); o3[j] = v >= 0.f ? v : a * v;
        }
        *(f4*)&yr[pg * 4]       = o1;
        *(f4*)&yr[64 + pg * 4]  = o2;
        *(f2*)&yr[128 + pg * 2] = o3;
    }
}

// ---------------------------------------------------------------------------
// 2D transpose with optional residual add (single batch).
// out[m][n] = in[n][m] (+ res[m][n]);  in: (No, Mo)  out: (Mo, No)
// ---------------------------------------------------------------------------
__global__ __launch_bounds__(256)
void transpose_res(const float* __restrict__ in, const float* __restrict__ res,
                   float* __restrict__ out, int Mo, int No)
{
    __shared__ float tile[32][33];
    const int n0 = blockIdx.x * 32, m0 = blockIdx.y * 32;
    const int tx = threadIdx.x, ty = threadIdx.y;
#pragma unroll
    for (int i = 0; i < 32; i += 8)
        tile[ty + i][tx] = in[(size_t)(n0 + ty + i) * Mo + (m0 + tx)];
    __syncthreads();
#pragma unroll
    for (int i = 0; i < 32; i += 8) {
        const size_t oidx = (size_t)(m0 + ty + i) * No + (n0 + tx);
        float v = tile[tx][ty + i];
        if (res) v += res[oidx];
        out[oidx] = v;
    }
}

// ---------------------------------------------------------------------------
// Fused attention (single batch): S = softmax(Q^T K / sqrt(C)); O = V @ P^T
// MODE 0 (f-attn): groups t in [0,320), NY=256, channel stride TF_
// MODE 1 (t-attn): groups f in [0,256), NY=320, channel stride T_
// Column ownership: thread tx owns columns {c4*64 + tx*4 + j}: 2-way-free
// LDS reads AND compile-time accumulator indices (round-2 lesson).
// ---------------------------------------------------------------------------
template<int MODE>
__global__ __launch_bounds__(256)
void attn_kernel(const float* __restrict__ Qb, const float* __restrict__ Kb,
                 const float* __restrict__ Vb, float* __restrict__ Ob)
{
    constexpr int NY   = (MODE == 0) ? 256 : 320;
    constexpr int LD   = (MODE == 0) ? TF_ : T_;
    constexpr int NJ   = NY / 16;          // per-thread y count (16 / 20)
    constexpr int NC4  = NJ / 4;           // float4 chunks (4 / 5)
    constexpr int PPAD = NY + 4;           // 260 / 324
    constexpr int SPG  = (MODE == 0) ? (F_ / 64) : (T_ / 64);
    constexpr int GOFF = (MODE == 0) ? F_ : C_ * T_;

    extern __shared__ float lds[];
    float* Alds = lds;            // Q strip [96][64] then V tile [64][100]
    float* Blds = lds + 6400;     // K [96][NY]      then P [64][PPAD]

    const int strip = blockIdx.x % SPG;
    const int grp   = blockIdx.x / SPG;
    const int m0    = strip * 64;
    const size_t off = (size_t)grp * GOFF;
    const float* Q = Qb + off;
    const float* K = Kb + off;
    const float* V = Vb + off;
    float*       O = Ob + off;

    const int tid = threadIdx.x;
    for (int e = tid; e < 96 * 64; e += 256) {
        const int kk = e >> 6, mm = e & 63;
        Alds[kk * 64 + mm] = Q[(size_t)kk * LD + m0 + mm];
    }
    for (int e = tid; e < 96 * NY; e += 256) {
        const int kk = e / NY, nn = e - kk * NY;
        Blds[kk * NY + nn] = K[(size_t)kk * LD + nn];
    }
    __syncthreads();

    const int ty = tid >> 4, tx = tid & 15;
    float s[4][NJ];
#pragma unroll
    for (int i = 0; i < 4; ++i)
#pragma unroll
        for (int j = 0; j < NJ; ++j) s[i][j] = 0.f;

    for (int kk = 0; kk < 96; ++kk) {
        const f4 qv = *(const f4*)&Alds[kk * 64 + ty * 4];
#pragma unroll
        for (int c4 = 0; c4 < NC4; ++c4) {
            const f4 kv = *(const f4*)&Blds[kk * NY + c4 * 64 + tx * 4];
#pragma unroll
            for (int i = 0; i < 4; ++i) {
#pragma unroll
                for (int j = 0; j < 4; ++j)
                    s[i][c4 * 4 + j] = fmaf(qv[i], kv[j], s[i][c4 * 4 + j]);
            }
        }
    }
    __syncthreads();

    const float scale = 0.10206207261596575f;   // 1/sqrt(96)
#pragma unroll
    for (int i = 0; i < 4; ++i) {
#pragma unroll
        for (int j = 0; j < NJ; ++j) s[i][j] *= scale;
        float m = s[i][0];
#pragma unroll
        for (int j = 1; j < NJ; ++j) m = fmaxf(m, s[i][j]);
        for (int d = 1; d < 16; d <<= 1) m = fmaxf(m, __shfl_xor(m, d));
        float l = 0.f;
#pragma unroll
        for (int j = 0; j < NJ; ++j) { s[i][j] = __expf(s[i][j] - m); l += s[i][j]; }
        for (int d = 1; d < 16; d <<= 1) l += __shfl_xor(l, d);
        const float inv = 1.f / l;
#pragma unroll
        for (int j = 0; j < NJ; ++j) s[i][j] *= inv;
    }
#pragma unroll
    for (int i = 0; i < 4; ++i) {
#pragma unroll
        for (int c4 = 0; c4 < NC4; ++c4) {
            f4 w; w[0] = s[i][c4*4]; w[1] = s[i][c4*4+1];
                  w[2] = s[i][c4*4+2]; w[3] = s[i][c4*4+3];
            *(f4*)&Blds[(ty * 4 + i) * PPAD + c4 * 64 + tx * 4] = w;
        }
    }

    const int cg = tid & 7, fg = tid >> 3;
    float accA[12], accB[12];
#pragma unroll
    for (int i = 0; i < 12; ++i) { accA[i] = 0.f; accB[i] = 0.f; }

    for (int yt = 0; yt < NY / 64; ++yt) {
        __syncthreads();
        for (int e = tid; e < 96 * 64; e += 256) {      // V tile, transposed store
            const int cI = e >> 6, yI = e & 63;
            Alds[yI * 100 + cI] = V[(size_t)cI * LD + yt * 64 + yI];
        }
        __syncthreads();
        const float* Prow0 = &Blds[(2 * fg) * PPAD + yt * 64];
        const float* Prow1 = Prow0 + PPAD;
        for (int y = 0; y < 64; ++y) {
            const f4 va = *(const f4*)&Alds[y * 100 + cg * 12];
            const f4 vb = *(const f4*)&Alds[y * 100 + cg * 12 + 4];
            const f4 vc = *(const f4*)&Alds[y * 100 + cg * 12 + 8];
            const float p0 = Prow0[y], p1 = Prow1[y];
#pragma unroll
            for (int i = 0; i < 4; ++i) {
                accA[i]     = fmaf(va[i], p0, accA[i]);
                accB[i]     = fmaf(va[i], p1, accB[i]);
                accA[4 + i] = fmaf(vb[i], p0, accA[4 + i]);
                accB[4 + i] = fmaf(vb[i], p1, accB[4 + i]);
                accA[8 + i] = fmaf(vc[i], p0, accA[8 + i]);
                accB[8 + i] = fmaf(vc[i], p1, accB[8 + i]);
            }
        }
    }
#pragma unroll
    for (int i = 0; i < 12; ++i) {
        f2 w; w[0] = accA[i]; w[1] = accB[i];
        *(f2*)&O[(size_t)(cg * 12 + i) * LD + m0 + 2 * fg] = w;
    }
}

// ---------------------------------------------------------------------------
extern "C" void kernel_launch(void* const* d_in, const int* in_sizes, int n_in,
                              void* d_out, int out_size, void* d_ws, size_t ws_size,
                              hipStream_t stream)
{
    const float* inp = (const float*)d_in[0];
    const float* W_f = (const float*)d_in[1];  const float* b_f = (const float*)d_in[2];
    const float* g_f = (const float*)d_in[3];  const float* be_f = (const float*)d_in[4];
    const float* m_f = (const float*)d_in[5];  const float* v_f = (const float*)d_in[6];
    const float* a_f = (const float*)d_in[7];
    const float* W_t = (const float*)d_in[8];  const float* b_t = (const float*)d_in[9];
    const float* g_t = (const float*)d_in[10]; const float* be_t = (const float*)d_in[11];
    const float* m_t = (const float*)d_in[12]; const float* v_t = (const float*)d_in[13];
    const float* a_t = (const float*)d_in[14];
    const float* W_p = (const float*)d_in[15]; const float* b_p = (const float*)d_in[16];
    const float* g_p = (const float*)d_in[17]; const float* be_p = (const float*)d_in[18];
    const float* m_p = (const float*)d_in[19]; const float* v_p = (const float*)d_in[20];
    const float* a_p = (const float*)d_in[21];

    hipFuncSetAttribute((const void*)conv_gemm<288>,
                        hipFuncAttributeMaxDynamicSharedMemorySize, 98304);
    hipFuncSetAttribute((const void*)conv_gemm<192>,
                        hipFuncAttributeMaxDynamicSharedMemorySize, 98304);
    hipFuncSetAttribute((const void*)conv_gemm<96>,
                        hipFuncAttributeMaxDynamicSharedMemorySize, 98304);
    hipFuncSetAttribute((const void*)attn_kernel<0>,
                        hipFuncAttributeMaxDynamicSharedMemorySize, 123904);
    hipFuncSetAttribute((const void*)attn_kernel<1>,
                        hipFuncAttributeMaxDynamicSharedMemorySize, 148480);

    // Per-batch pipeline; ws = 3 quarter-buffers (94.4 MB), d_out as scratch.
    constexpr size_t QH = (size_t)C_ * T_ * F_;   // 7,864,320 floats
    float* ws = (float*)d_ws;

    for (int b = 0; b < B_; ++b) {
        const float* xb  = inp + (size_t)b * QH;
        float*       dob = (float*)d_out + (size_t)b * QH;
        float* fqkv  = ws;            // [0,3Q)  step1 -> dead after step2
        float* foutT = ws;            // [0,Q)   step3 -> V of t-attn
        float* th2   = ws + QH;       // [Q,3Q)  step4 (192-out conv_t)
        float* tkT   = ws + QH;       // [Q,2Q)  step6 (th2 q-half dead)
        float* tout  = ws + 2 * QH;   // [2Q,3Q) step7 (th2 k-half dead)
        float* tmp   = ws + QH;       // [Q,2Q)  step8 (tkT dead)

        // 1. f_qkv = cbp_f(inp_b)              (3C, T, F)
        conv_gemm<288><<<dim3(3 * 512), dim3(256), 98304, stream>>>(
            xb, W_f, b_f, g_f, be_f, m_f, v_f, a_f, fqkv, TF_, 512);
        // 2. f-attention -> fout in d_out slice (C, T, F)
        attn_kernel<0><<<dim3(T_ * (F_ / 64)), dim3(256), 123904, stream>>>(
            fqkv, fqkv + (size_t)C_ * TF_, fqkv + (size_t)2 * C_ * TF_, dob);
        // 3. foutT = transpose(fout)            (F, C, T)
        transpose_res<<<dim3(960, 8, 1), dim3(32, 8), 0, stream>>>(
            dob, nullptr, foutT, F_, C_ * T_);
        // 4. th2 = cbp_t(inp_b)                 (2C, T, F)
        conv_gemm<192><<<dim3(2 * 512), dim3(256), 98304, stream>>>(
            xb, W_t, b_t, g_t, be_t, m_t, v_t, a_t, th2, TF_, 512);
        // 5. tqT = transpose(th2 q-half) -> d_out slice (fout dead)
        transpose_res<<<dim3(960, 8, 1), dim3(32, 8), 0, stream>>>(
            th2, nullptr, dob, F_, C_ * T_);
        // 6. tkT = transpose(th2 k-half)        (F, C, T)
        transpose_res<<<dim3(960, 8, 1), dim3(32, 8), 0, stream>>>(
            th2 + QH, nullptr, tkT, F_, C_ * T_);
        // 7. t-attention(Q=tqT, K=tkT, V=foutT) -> tout  (F, C, T)
        attn_kernel<1><<<dim3(F_ * (T_ / 64)), dim3(256), 148480, stream>>>(
            dob, tkT, foutT, tout);
        // 8. tmp = cbp_p(tout), groups f        (F, C, T)
        conv_gemm<96><<<dim3(256 * 2), dim3(256), 98304, stream>>>(
            tout, W_p, b_p, g_p, be_p, m_p, v_p, a_p, tmp, T_, 2);
        // 9. out_b = transpose(tmp) + inp_b     (C, T, F)
        transpose_res<<<dim3(8, 960, 1), dim3(32, 8), 0, stream>>>(
            tmp, xb, dob, C_ * T_, F_);
    }
}

// Round 5
// 2003.694 us; speedup vs baseline: 18.6216x; 1.5295x over previous
//
#include <hip/hip_runtime.h>
#include <math.h>

typedef float f4 __attribute__((ext_vector_type(4)));
typedef float f2 __attribute__((ext_vector_type(2)));
typedef _Float16 h8 __attribute__((ext_vector_type(8)));

constexpr int B_ = 4, C_ = 96, T_ = 320, F_ = 256;
constexpr int TF_ = T_ * F_;          // 81920
constexpr float EPS_ = 1e-5f;

// ---------------------------------------------------------------------------
// Tiled 1x1-conv GEMM + BN + PReLU.  y[g][co][p] = act(BN(sum_k W[co][k] x[g][k][p]))
// Block: 256 threads, tile = 96 co x 160 p, K = 96 single-shot in LDS.
// ---------------------------------------------------------------------------
template<int COUT>
__global__ __launch_bounds__(256)
void conv_gemm(const float* __restrict__ x, const float* __restrict__ W,
               const float* __restrict__ bias, const float* __restrict__ gamma,
               const float* __restrict__ beta, const float* __restrict__ mean,
               const float* __restrict__ var,  const float* __restrict__ aP,
               float* __restrict__ y, int P, int ptilesPerG)
{
    constexpr int NCO = COUT / 96;
    extern __shared__ float lds[];
    float* Xs = lds;              // [96][160]
    float* Wt = lds + 96 * 160;   // [96 kk][96 co]

    const int tid = threadIdx.x;
    const int pt  = blockIdx.x % ptilesPerG;
    const int cot = (blockIdx.x / ptilesPerG) % NCO;
    const int g   = blockIdx.x / (ptilesPerG * NCO);
    const int p0  = pt * 160;

    const float* xg = x + (size_t)g * 96 * P + p0;
    for (int e = tid; e < 96 * 40; e += 256) {
        const int kk = e / 40, ch = e - kk * 40;
        *(f4*)&Xs[kk * 160 + ch * 4] = *(const f4*)&xg[(size_t)kk * P + ch * 4];
    }
    const float* wg = W + (size_t)cot * 96 * 96;
    for (int e = tid; e < 96 * 96; e += 256) {
        const int co = e % 96, kk = e / 96;
        Wt[kk * 96 + co] = wg[(size_t)co * 96 + kk];
    }
    __syncthreads();

    const int cg = tid >> 4, pg = tid & 15;
    const float* xbase = Xs + pg * 4;
    const float* wbase = Wt + cg * 6;
    float acc[6][10];
#pragma unroll
    for (int i = 0; i < 6; ++i)
#pragma unroll
        for (int j = 0; j < 10; ++j) acc[i][j] = 0.f;

#pragma unroll 2
    for (int kk = 0; kk < 96; ++kk) {
        const float* xr = xbase + kk * 160;
        const float* wr = wbase + kk * 96;
        const f4 xA = *(const f4*)xr;
        const f4 xB = *(const f4*)(xr + 64);
        const f2 xC = *(const f2*)(Xs + kk * 160 + 128 + pg * 2);
        const f2 wA = *(const f2*)wr;
        const f2 wB = *(const f2*)(wr + 2);
        const f2 wC = *(const f2*)(wr + 4);
        const float xv[10] = {xA[0],xA[1],xA[2],xA[3], xB[0],xB[1],xB[2],xB[3],
                              xC[0],xC[1]};
        const float wv[6]  = {wA[0],wA[1], wB[0],wB[1], wC[0],wC[1]};
#pragma unroll
        for (int i = 0; i < 6; ++i)
#pragma unroll
            for (int j = 0; j < 10; ++j)
                acc[i][j] = fmaf(wv[i], xv[j], acc[i][j]);
    }

    const float a = aP[0];
    const int coBase = cot * 96 + cg * 6;
#pragma unroll
    for (int i = 0; i < 6; ++i) {
        const int co = coBase + i;
        const float sc = gamma[co] * rsqrtf(var[co] + EPS_);
        const float sh = fmaf(bias[co] - mean[co], sc, beta[co]);
        float* yr = y + ((size_t)g * COUT + co) * P + p0;
        f4 o1, o2; f2 o3;
#pragma unroll
        for (int j = 0; j < 4; ++j) {
            float v = fmaf(acc[i][j], sc, sh);     o1[j] = v >= 0.f ? v : a * v;
            float w = fmaf(acc[i][4 + j], sc, sh); o2[j] = w >= 0.f ? w : a * w;
        }
#pragma unroll
        for (int j = 0; j < 2; ++j) {
            float v = fmaf(acc[i][8 + j], sc, sh); o3[j] = v >= 0.f ? v : a * v;
        }
        *(f4*)&yr[pg * 4]       = o1;
        *(f4*)&yr[64 + pg * 4]  = o2;
        *(f2*)&yr[128 + pg * 2] = o3;
    }
}

// ---------------------------------------------------------------------------
// 2D transpose with optional residual add (single batch).
// ---------------------------------------------------------------------------
__global__ __launch_bounds__(256)
void transpose_res(const float* __restrict__ in, const float* __restrict__ res,
                   float* __restrict__ out, int Mo, int No)
{
    __shared__ float tile[32][33];
    const int n0 = blockIdx.x * 32, m0 = blockIdx.y * 32;
    const int tx = threadIdx.x, ty = threadIdx.y;
#pragma unroll
    for (int i = 0; i < 32; i += 8)
        tile[ty + i][tx] = in[(size_t)(n0 + ty + i) * Mo + (m0 + tx)];
    __syncthreads();
#pragma unroll
    for (int i = 0; i < 32; i += 8) {
        const size_t oidx = (size_t)(m0 + ty + i) * No + (n0 + tx);
        float v = tile[tx][ty + i];
        if (res) v += res[oidx];
        out[oidx] = v;
    }
}

// ---------------------------------------------------------------------------
// MFMA f16 fused attention (single batch).
// S = softmax(Q^T K * scale); O = V P^T.
// MODE 0: groups t (320), NY=256, LD=TF_.  MODE 1: groups f (256), NY=320, LD=T_.
// Block = 64-row S strip, 4 waves x 16 rows.
// LDS (f16): Qt[64][104] (c-contig, scale folded in), Kt[NY][104] (c-contig),
// then V[96][NY+24] over dead Kt, P[64][NY+24].  All MFMA operand reads are
// single ds_read_b128 with <=2-way bank aliasing.
// QK^T: D=A(Q^T)xB(K) -> lane holds S[row=mw+lg*4+r][y=t*16+l16] (guide-verified
// C/D map) -> softmax via 16-lane shfl_xor.  PV swaps roles (A=V, B=P^T; the
// B-frag of P^T is this wave's own A-frag of P) -> D[c][m], coalesced stores.
// ---------------------------------------------------------------------------
template<int MODE>
__global__ __launch_bounds__(256)
void attn_mfma(const float* __restrict__ Qb, const float* __restrict__ Kb,
               const float* __restrict__ Vb, float* __restrict__ Ob)
{
    constexpr int NY  = (MODE == 0) ? 256 : 320;
    constexpr int LD  = (MODE == 0) ? TF_ : T_;
    constexpr int NT  = NY / 16;           // S col-tiles per wave (16 / 20)
    constexpr int NYK = NY / 32;           // PV k-iters (8 / 10)
    constexpr int QTS = 104;               // Qt/Kt stride in f16
    constexpr int VPS = NY + 24;           // V/P stride in f16 (280 / 344)
    constexpr int KVH = (NY * QTS > 96 * VPS) ? NY * QTS : 96 * VPS;
    constexpr int SPG = (MODE == 0) ? (F_ / 64) : (T_ / 64);
    constexpr int GOFF = (MODE == 0) ? F_ : C_ * T_;

    extern __shared__ _Float16 ldsh[];
    _Float16* Qt = ldsh;                     // [64][QTS]
    _Float16* KV = ldsh + 64 * QTS;          // Kt[NY][QTS] -> V[96][VPS]
    _Float16* Ps = ldsh + 64 * QTS + KVH;    // [64][VPS]

    const int strip = blockIdx.x % SPG;
    const int grp   = blockIdx.x / SPG;
    const int m0    = strip * 64;
    const size_t off = (size_t)grp * GOFF;
    const float* Q = Qb + off;
    const float* K = Kb + off;
    const float* V = Vb + off;
    float*       O = Ob + off;

    const int tid  = threadIdx.x;
    const int lane = tid & 63, wid = tid >> 6;
    const int l16  = lane & 15, lg = lane >> 4;
    const int mw   = wid * 16;
    const float scale = 0.10206207261596575f;   // 1/sqrt(96)

    // ---- stage Qt[m][c] (scale folded) and Kt[y][c] ----
    for (int e = tid; e < 96 * 64; e += 256) {
        const int c = e >> 6, m = e & 63;
        Qt[m * QTS + c] = (_Float16)(Q[(size_t)c * LD + m0 + m] * scale);
    }
    for (int e = tid; e < 96 * NY; e += 256) {
        const int c = e / NY, yy = e - c * NY;
        KV[yy * QTS + c] = (_Float16)K[(size_t)c * LD + yy];
    }
    __syncthreads();

    // ---- S strip: 16 rows per wave, NT col tiles, K=96 in 3 mfma steps ----
    f32x4_t: ;
    typedef float f32x4 __attribute__((ext_vector_type(4)));
    f32x4 sacc[NT];
#pragma unroll
    for (int t = 0; t < NT; ++t) sacc[t] = (f32x4){0.f, 0.f, 0.f, 0.f};

#pragma unroll
    for (int kk = 0; kk < 3; ++kk) {
        const h8 aQ = *(const h8*)&Qt[(mw + l16) * QTS + kk * 32 + lg * 8];
#pragma unroll
        for (int t = 0; t < NT; ++t) {
            const h8 bK = *(const h8*)&KV[(t * 16 + l16) * QTS + kk * 32 + lg * 8];
            sacc[t] = __builtin_amdgcn_mfma_f32_16x16x32_f16(aQ, bK, sacc[t], 0, 0, 0);
        }
    }
    __syncthreads();    // Kt reads complete; KV region may be overwritten by V

    // ---- softmax on rows (lane holds S[mw+lg*4+r][t*16+l16]) -> P (f16) ----
#pragma unroll
    for (int r = 0; r < 4; ++r) {
        float mx = sacc[0][r];
#pragma unroll
        for (int t = 1; t < NT; ++t) mx = fmaxf(mx, sacc[t][r]);
        for (int d = 1; d < 16; d <<= 1) mx = fmaxf(mx, __shfl_xor(mx, d));
        float pv[NT];
        float sum = 0.f;
#pragma unroll
        for (int t = 0; t < NT; ++t) { pv[t] = __expf(sacc[t][r] - mx); sum += pv[t]; }
        for (int d = 1; d < 16; d <<= 1) sum += __shfl_xor(sum, d);
        const float inv = 1.f / sum;
        const int row = mw + lg * 4 + r;
#pragma unroll
        for (int t = 0; t < NT; ++t)
            Ps[row * VPS + t * 16 + l16] = (_Float16)(pv[t] * inv);
    }

    // ---- stage V[c][y] (f16, b128 writes) into dead Kt region ----
    constexpr int NY8 = NY / 8;
    for (int e = tid; e < 96 * NY8; e += 256) {
        const int c = e / NY8, y8 = e - c * NY8;
        const float* vp = V + (size_t)c * LD + y8 * 8;
        h8 hv;
#pragma unroll
        for (int j = 0; j < 8; ++j) hv[j] = (_Float16)vp[j];
        *(h8*)&KV[c * VPS + y8 * 8] = hv;
    }
    __syncthreads();

    // ---- O = V P^T : A=V rows(c), B=P^T cols(m = this wave's rows) ----
    h8 pf[NYK];
#pragma unroll
    for (int yk = 0; yk < NYK; ++yk)
        pf[yk] = *(const h8*)&Ps[(mw + l16) * VPS + yk * 32 + lg * 8];

#pragma unroll
    for (int ct = 0; ct < 6; ++ct) {
        f32x4 oacc = (f32x4){0.f, 0.f, 0.f, 0.f};
#pragma unroll
        for (int yk = 0; yk < NYK; ++yk) {
            const h8 av = *(const h8*)&KV[(ct * 16 + l16) * VPS + yk * 32 + lg * 8];
            oacc = __builtin_amdgcn_mfma_f32_16x16x32_f16(av, pf[yk], oacc, 0, 0, 0);
        }
        // D: row c = ct*16 + lg*4 + r, col m = mw + l16  -> coalesced 64B lines
#pragma unroll
        for (int r = 0; r < 4; ++r)
            O[(size_t)(ct * 16 + lg * 4 + r) * LD + m0 + mw + l16] = oacc[r];
    }
}

// ---------------------------------------------------------------------------
extern "C" void kernel_launch(void* const* d_in, const int* in_sizes, int n_in,
                              void* d_out, int out_size, void* d_ws, size_t ws_size,
                              hipStream_t stream)
{
    const float* inp = (const float*)d_in[0];
    const float* W_f = (const float*)d_in[1];  const float* b_f = (const float*)d_in[2];
    const float* g_f = (const float*)d_in[3];  const float* be_f = (const float*)d_in[4];
    const float* m_f = (const float*)d_in[5];  const float* v_f = (const float*)d_in[6];
    const float* a_f = (const float*)d_in[7];
    const float* W_t = (const float*)d_in[8];  const float* b_t = (const float*)d_in[9];
    const float* g_t = (const float*)d_in[10]; const float* be_t = (const float*)d_in[11];
    const float* m_t = (const float*)d_in[12]; const float* v_t = (const float*)d_in[13];
    const float* a_t = (const float*)d_in[14];
    const float* W_p = (const float*)d_in[15]; const float* b_p = (const float*)d_in[16];
    const float* g_p = (const float*)d_in[17]; const float* be_p = (const float*)d_in[18];
    const float* m_p = (const float*)d_in[19]; const float* v_p = (const float*)d_in[20];
    const float* a_p = (const float*)d_in[21];

    hipFuncSetAttribute((const void*)conv_gemm<288>,
                        hipFuncAttributeMaxDynamicSharedMemorySize, 98304);
    hipFuncSetAttribute((const void*)conv_gemm<192>,
                        hipFuncAttributeMaxDynamicSharedMemorySize, 98304);
    hipFuncSetAttribute((const void*)conv_gemm<96>,
                        hipFuncAttributeMaxDynamicSharedMemorySize, 98304);
    hipFuncSetAttribute((const void*)attn_mfma<0>,
                        hipFuncAttributeMaxDynamicSharedMemorySize, 102912);
    hipFuncSetAttribute((const void*)attn_mfma<1>,
                        hipFuncAttributeMaxDynamicSharedMemorySize, 123904);

    // Per-batch pipeline; ws = 3 quarter-buffers (94.4 MB), d_out as scratch.
    constexpr size_t QH = (size_t)C_ * T_ * F_;   // 7,864,320 floats
    float* ws = (float*)d_ws;

    for (int b = 0; b < B_; ++b) {
        const float* xb  = inp + (size_t)b * QH;
        float*       dob = (float*)d_out + (size_t)b * QH;
        float* fqkv  = ws;            // [0,3Q)  step1 -> dead after step2
        float* foutT = ws;            // [0,Q)   step3 -> V of t-attn
        float* th2   = ws + QH;       // [Q,3Q)  step4 (192-out conv_t)
        float* tkT   = ws + QH;       // [Q,2Q)  step6
        float* tout  = ws + 2 * QH;   // [2Q,3Q) step7
        float* tmp   = ws + QH;       // [Q,2Q)  step8

        // 1. f_qkv = cbp_f(inp_b)              (3C, T, F)
        conv_gemm<288><<<dim3(3 * 512), dim3(256), 98304, stream>>>(
            xb, W_f, b_f, g_f, be_f, m_f, v_f, a_f, fqkv, TF_, 512);
        // 2. f-attention -> fout in d_out slice (C, T, F)
        attn_mfma<0><<<dim3(T_ * (F_ / 64)), dim3(256), 102912, stream>>>(
            fqkv, fqkv + (size_t)C_ * TF_, fqkv + (size_t)2 * C_ * TF_, dob);
        // 3. foutT = transpose(fout)            (F, C, T)
        transpose_res<<<dim3(960, 8, 1), dim3(32, 8), 0, stream>>>(
            dob, nullptr, foutT, F_, C_ * T_);
        // 4. th2 = cbp_t(inp_b)                 (2C, T, F)
        conv_gemm<192><<<dim3(2 * 512), dim3(256), 98304, stream>>>(
            xb, W_t, b_t, g_t, be_t, m_t, v_t, a_t, th2, TF_, 512);
        // 5. tqT = transpose(th2 q-half) -> d_out slice (fout dead)
        transpose_res<<<dim3(960, 8, 1), dim3(32, 8), 0, stream>>>(
            th2, nullptr, dob, F_, C_ * T_);
        // 6. tkT = transpose(th2 k-half)        (F, C, T)
        transpose_res<<<dim3(960, 8, 1), dim3(32, 8), 0, stream>>>(
            th2 + QH, nullptr, tkT, F_, C_ * T_);
        // 7. t-attention(Q=tqT, K=tkT, V=foutT) -> tout  (F, C, T)
        attn_mfma<1><<<dim3(F_ * (T_ / 64)), dim3(256), 123904, stream>>>(
            dob, tkT, foutT, tout);
        // 8. tmp = cbp_p(tout), groups f        (F, C, T)
        conv_gemm<96><<<dim3(256 * 2), dim3(256), 98304, stream>>>(
            tout, W_p, b_p, g_p, be_p, m_p, v_p, a_p, tmp, T_, 2);
        // 9. out_b = transpose(tmp) + inp_b     (C, T, F)
        transpose_res<<<dim3(8, 960, 1), dim3(32, 8), 0, stream>>>(
            tmp, xb, dob, C_ * T_, F_);
    }
}

// Round 6
// 1535.758 us; speedup vs baseline: 24.2955x; 1.3047x over previous
//
#include <hip/hip_runtime.h>
#include <math.h>

typedef float f4 __attribute__((ext_vector_type(4)));
typedef float f2 __attribute__((ext_vector_type(2)));
typedef float f32x4 __attribute__((ext_vector_type(4)));
typedef _Float16 h8 __attribute__((ext_vector_type(8)));
typedef _Float16 h4 __attribute__((ext_vector_type(4)));

constexpr int B_ = 4, C_ = 96, T_ = 320, F_ = 256;
constexpr int TF_ = T_ * F_;          // 81920
constexpr float EPS_ = 1e-5f;

// ---------------------------------------------------------------------------
// MFMA 1x1-conv GEMM + BN + PReLU, f16 two-term split (fp32-accurate):
//   x = xh + xl, w = wh + wl;  x*w ~= xh*wh + xh*wl + xl*wh   (drop ~2^-22 term)
// y[g][co][p] = act(BN(sum_k W[co][k] x[g][k][p]))
// Block: 256 thr (2x2 waves), tile = 96 co x PT p, K'=192 (hi||lo) in LDS.
// Xs[p][200] k-contiguous (gather-8k staging -> b128 writes); Ws[co][200].
// Wave: 3 Mtiles x (PT/32) Ntiles; A-frags preloaded (18 h8), B streamed.
// ---------------------------------------------------------------------------
template<int COUT, int PT>
__global__ __launch_bounds__(256)
void conv_mfma(const float* __restrict__ x, const float* __restrict__ W,
               const float* __restrict__ bias, const float* __restrict__ gamma,
               const float* __restrict__ beta, const float* __restrict__ mean,
               const float* __restrict__ var,  const float* __restrict__ aP,
               float* __restrict__ y, int P, int ptilesPerG)
{
    constexpr int NCO = COUT / 96;
    constexpr int NN  = (PT / 16) / 2;     // N-tiles per wave (4 | 5)
    constexpr int LS  = 200;               // LDS row stride (f16 elems)
    extern __shared__ _Float16 ldsh[];
    _Float16* Xs = ldsh;                   // [PT][LS]  cols: 0-95 hi, 96-191 lo
    _Float16* Ws = ldsh + PT * LS;         // [96][LS]

    const int tid = threadIdx.x;
    const int pt  = blockIdx.x % ptilesPerG;
    const int cot = (blockIdx.x / ptilesPerG) % NCO;
    const int g   = blockIdx.x / (ptilesPerG * NCO);
    const int p0  = pt * PT;

    // ---- stage X: thread gathers 8 k for fixed p (loads lane-coalesced on p)
    const float* xg = x + (size_t)g * 96 * P + p0;
    for (int e = tid; e < PT * 12; e += 256) {
        const int p = e % PT, k0 = (e / PT) * 8;
        const float* xp = xg + (size_t)k0 * P + p;
        h8 hv, lv;
#pragma unroll
        for (int j = 0; j < 8; ++j) {
            const float xv = xp[(size_t)j * P];
            const _Float16 xh = (_Float16)xv;
            hv[j] = xh;
            lv[j] = (_Float16)(xv - (float)xh);
        }
        *(h8*)&Xs[p * LS + k0]      = hv;
        *(h8*)&Xs[p * LS + 96 + k0] = lv;
    }
    // ---- stage W (rows already k-contiguous in global)
    const float* wg = W + (size_t)cot * 96 * 96;
    for (int e = tid; e < 96 * 24; e += 256) {
        const f4 wv = *(const f4*)&wg[e * 4];
        const int co = e / 24, k = (e % 24) * 4;
        h4 hv, lv;
#pragma unroll
        for (int j = 0; j < 4; ++j) {
            const _Float16 wh = (_Float16)wv[j];
            hv[j] = wh;
            lv[j] = (_Float16)(wv[j] - (float)wh);
        }
        *(h4*)&Ws[co * LS + k]      = hv;
        *(h4*)&Ws[co * LS + 96 + k] = lv;
    }
    __syncthreads();

    const int lane = tid & 63, wid = tid >> 6;
    const int l16 = lane & 15, lg = lane >> 4;
    const int wm = wid >> 1, wn = wid & 1;       // 2x2 wave grid

    // ---- preload A-frags: 3 Mtiles x 6 k-steps (wh0-2, wl0-2; col = wk*32)
    h8 af[3][6];
#pragma unroll
    for (int mt = 0; mt < 3; ++mt)
#pragma unroll
        for (int wk = 0; wk < 6; ++wk)
            af[mt][wk] = *(const h8*)&Ws[((wm * 3 + mt) * 16 + l16) * LS + wk * 32 + lg * 8];

    f32x4 acc[3][NN];
#pragma unroll
    for (int mt = 0; mt < 3; ++mt)
#pragma unroll
        for (int nn = 0; nn < NN; ++nn) acc[mt][nn] = (f32x4){0.f, 0.f, 0.f, 0.f};

#pragma unroll
    for (int xk = 0; xk < 6; ++xk) {             // 0-2: Xh, 3-5: Xl
        h8 bf[NN];
#pragma unroll
        for (int nn = 0; nn < NN; ++nn)
            bf[nn] = *(const h8*)&Xs[((wn * NN + nn) * 16 + l16) * LS + xk * 32 + lg * 8];
        if (xk < 3) {
#pragma unroll
            for (int mt = 0; mt < 3; ++mt)
#pragma unroll
                for (int nn = 0; nn < NN; ++nn) {
                    acc[mt][nn] = __builtin_amdgcn_mfma_f32_16x16x32_f16(
                        af[mt][xk], bf[nn], acc[mt][nn], 0, 0, 0);       // xh*wh
                    acc[mt][nn] = __builtin_amdgcn_mfma_f32_16x16x32_f16(
                        af[mt][xk + 3], bf[nn], acc[mt][nn], 0, 0, 0);   // xh*wl
                }
        } else {
#pragma unroll
            for (int mt = 0; mt < 3; ++mt)
#pragma unroll
                for (int nn = 0; nn < NN; ++nn)
                    acc[mt][nn] = __builtin_amdgcn_mfma_f32_16x16x32_f16(
                        af[mt][xk - 3], bf[nn], acc[mt][nn], 0, 0, 0);   // xl*wh
        }
    }

    // ---- BN + PReLU epilogue; D: row co = lg*4+r (within Mtile), col p = l16
    const float a = aP[0];
    const int cobase = cot * 96;
#pragma unroll
    for (int mt = 0; mt < 3; ++mt) {
#pragma unroll
        for (int r = 0; r < 4; ++r) {
            const int co = cobase + (wm * 3 + mt) * 16 + lg * 4 + r;
            const float sc = gamma[co] * rsqrtf(var[co] + EPS_);
            const float sh = fmaf(bias[co] - mean[co], sc, beta[co]);
            float* yr = y + ((size_t)g * COUT + co) * P + p0 + wn * NN * 16 + l16;
#pragma unroll
            for (int nn = 0; nn < NN; ++nn) {
                const float v = fmaf(acc[mt][nn][r], sc, sh);
                yr[nn * 16] = v >= 0.f ? v : a * v;
            }
        }
    }
}

// ---------------------------------------------------------------------------
// 2D transpose with optional residual add (single batch).
// ---------------------------------------------------------------------------
__global__ __launch_bounds__(256)
void transpose_res(const float* __restrict__ in, const float* __restrict__ res,
                   float* __restrict__ out, int Mo, int No)
{
    __shared__ float tile[32][33];
    const int n0 = blockIdx.x * 32, m0 = blockIdx.y * 32;
    const int tx = threadIdx.x, ty = threadIdx.y;
#pragma unroll
    for (int i = 0; i < 32; i += 8)
        tile[ty + i][tx] = in[(size_t)(n0 + ty + i) * Mo + (m0 + tx)];
    __syncthreads();
#pragma unroll
    for (int i = 0; i < 32; i += 8) {
        const size_t oidx = (size_t)(m0 + ty + i) * No + (n0 + tx);
        float v = tile[tx][ty + i];
        if (res) v += res[oidx];
        out[oidx] = v;
    }
}

// ---------------------------------------------------------------------------
// MFMA f16 fused attention (single batch).  S = softmax(Q^T K * scale); O = V P^T.
// MODE 0: groups t (320), NY=256, LD=TF_.  MODE 1: groups f (256), NY=320, LD=T_.
// ---------------------------------------------------------------------------
template<int MODE>
__global__ __launch_bounds__(256)
void attn_mfma(const float* __restrict__ Qb, const float* __restrict__ Kb,
               const float* __restrict__ Vb, float* __restrict__ Ob)
{
    constexpr int NY  = (MODE == 0) ? 256 : 320;
    constexpr int LD  = (MODE == 0) ? TF_ : T_;
    constexpr int NT  = NY / 16;           // S col-tiles per wave (16 / 20)
    constexpr int NYK = NY / 32;           // PV k-iters (8 / 10)
    constexpr int QTS = 104;               // Qt/Kt stride in f16
    constexpr int VPS = NY + 24;           // V/P stride in f16 (280 / 344)
    constexpr int KVH = (NY * QTS > 96 * VPS) ? NY * QTS : 96 * VPS;
    constexpr int SPG = (MODE == 0) ? (F_ / 64) : (T_ / 64);
    constexpr int GOFF = (MODE == 0) ? F_ : C_ * T_;

    extern __shared__ _Float16 ldsh[];
    _Float16* Qt = ldsh;                     // [64][QTS]
    _Float16* KV = ldsh + 64 * QTS;          // Kt[NY][QTS] -> V[96][VPS]
    _Float16* Ps = ldsh + 64 * QTS + KVH;    // [64][VPS]

    const int strip = blockIdx.x % SPG;
    const int grp   = blockIdx.x / SPG;
    const int m0    = strip * 64;
    const size_t off = (size_t)grp * GOFF;
    const float* Q = Qb + off;
    const float* K = Kb + off;
    const float* V = Vb + off;
    float*       O = Ob + off;

    const int tid  = threadIdx.x;
    const int lane = tid & 63, wid = tid >> 6;
    const int l16  = lane & 15, lg = lane >> 4;
    const int mw   = wid * 16;
    const float scale = 0.10206207261596575f;   // 1/sqrt(96)

    for (int e = tid; e < 96 * 64; e += 256) {
        const int c = e >> 6, m = e & 63;
        Qt[m * QTS + c] = (_Float16)(Q[(size_t)c * LD + m0 + m] * scale);
    }
    for (int e = tid; e < 96 * NY; e += 256) {
        const int c = e / NY, yy = e - c * NY;
        KV[yy * QTS + c] = (_Float16)K[(size_t)c * LD + yy];
    }
    __syncthreads();

    f32x4 sacc[NT];
#pragma unroll
    for (int t = 0; t < NT; ++t) sacc[t] = (f32x4){0.f, 0.f, 0.f, 0.f};

#pragma unroll
    for (int kk = 0; kk < 3; ++kk) {
        const h8 aQ = *(const h8*)&Qt[(mw + l16) * QTS + kk * 32 + lg * 8];
#pragma unroll
        for (int t = 0; t < NT; ++t) {
            const h8 bK = *(const h8*)&KV[(t * 16 + l16) * QTS + kk * 32 + lg * 8];
            sacc[t] = __builtin_amdgcn_mfma_f32_16x16x32_f16(aQ, bK, sacc[t], 0, 0, 0);
        }
    }
    __syncthreads();    // Kt reads complete; KV region reused for V

#pragma unroll
    for (int r = 0; r < 4; ++r) {
        float mx = sacc[0][r];
#pragma unroll
        for (int t = 1; t < NT; ++t) mx = fmaxf(mx, sacc[t][r]);
        for (int d = 1; d < 16; d <<= 1) mx = fmaxf(mx, __shfl_xor(mx, d));
        float pv[NT];
        float sum = 0.f;
#pragma unroll
        for (int t = 0; t < NT; ++t) { pv[t] = __expf(sacc[t][r] - mx); sum += pv[t]; }
        for (int d = 1; d < 16; d <<= 1) sum += __shfl_xor(sum, d);
        const float inv = 1.f / sum;
        const int row = mw + lg * 4 + r;
#pragma unroll
        for (int t = 0; t < NT; ++t)
            Ps[row * VPS + t * 16 + l16] = (_Float16)(pv[t] * inv);
    }

    constexpr int NY8 = NY / 8;
    for (int e = tid; e < 96 * NY8; e += 256) {
        const int c = e / NY8, y8 = e - c * NY8;
        const float* vp = V + (size_t)c * LD + y8 * 8;
        h8 hv;
#pragma unroll
        for (int j = 0; j < 8; ++j) hv[j] = (_Float16)vp[j];
        *(h8*)&KV[c * VPS + y8 * 8] = hv;
    }
    __syncthreads();

    h8 pf[NYK];
#pragma unroll
    for (int yk = 0; yk < NYK; ++yk)
        pf[yk] = *(const h8*)&Ps[(mw + l16) * VPS + yk * 32 + lg * 8];

#pragma unroll
    for (int ct = 0; ct < 6; ++ct) {
        f32x4 oacc = (f32x4){0.f, 0.f, 0.f, 0.f};
#pragma unroll
        for (int yk = 0; yk < NYK; ++yk) {
            const h8 av = *(const h8*)&KV[(ct * 16 + l16) * VPS + yk * 32 + lg * 8];
            oacc = __builtin_amdgcn_mfma_f32_16x16x32_f16(av, pf[yk], oacc, 0, 0, 0);
        }
#pragma unroll
        for (int r = 0; r < 4; ++r)
            O[(size_t)(ct * 16 + lg * 4 + r) * LD + m0 + mw + l16] = oacc[r];
    }
}

// ---------------------------------------------------------------------------
extern "C" void kernel_launch(void* const* d_in, const int* in_sizes, int n_in,
                              void* d_out, int out_size, void* d_ws, size_t ws_size,
                              hipStream_t stream)
{
    const float* inp = (const float*)d_in[0];
    const float* W_f = (const float*)d_in[1];  const float* b_f = (const float*)d_in[2];
    const float* g_f = (const float*)d_in[3];  const float* be_f = (const float*)d_in[4];
    const float* m_f = (const float*)d_in[5];  const float* v_f = (const float*)d_in[6];
    const float* a_f = (const float*)d_in[7];
    const float* W_t = (const float*)d_in[8];  const float* b_t = (const float*)d_in[9];
    const float* g_t = (const float*)d_in[10]; const float* be_t = (const float*)d_in[11];
    const float* m_t = (const float*)d_in[12]; const float* v_t = (const float*)d_in[13];
    const float* a_t = (const float*)d_in[14];
    const float* W_p = (const float*)d_in[15]; const float* b_p = (const float*)d_in[16];
    const float* g_p = (const float*)d_in[17]; const float* be_p = (const float*)d_in[18];
    const float* m_p = (const float*)d_in[19]; const float* v_p = (const float*)d_in[20];
    const float* a_p = (const float*)d_in[21];

    hipFuncSetAttribute((const void*)conv_mfma<288, 128>,
                        hipFuncAttributeMaxDynamicSharedMemorySize, 89600);
    hipFuncSetAttribute((const void*)conv_mfma<192, 128>,
                        hipFuncAttributeMaxDynamicSharedMemorySize, 89600);
    hipFuncSetAttribute((const void*)conv_mfma<96, 160>,
                        hipFuncAttributeMaxDynamicSharedMemorySize, 102400);
    hipFuncSetAttribute((const void*)attn_mfma<0>,
                        hipFuncAttributeMaxDynamicSharedMemorySize, 102912);
    hipFuncSetAttribute((const void*)attn_mfma<1>,
                        hipFuncAttributeMaxDynamicSharedMemorySize, 123904);

    // Per-batch pipeline; ws = 3 quarter-buffers (94.4 MB), d_out as scratch.
    constexpr size_t QH = (size_t)C_ * T_ * F_;   // 7,864,320 floats
    float* ws = (float*)d_ws;

    for (int b = 0; b < B_; ++b) {
        const float* xb  = inp + (size_t)b * QH;
        float*       dob = (float*)d_out + (size_t)b * QH;
        float* fqkv  = ws;            // [0,3Q)  step1 -> dead after step2
        float* foutT = ws;            // [0,Q)   step3 -> V of t-attn
        float* th2   = ws + QH;       // [Q,3Q)  step4 (192-out conv_t)
        float* tkT   = ws + QH;       // [Q,2Q)  step6
        float* tout  = ws + 2 * QH;   // [2Q,3Q) step7
        float* tmp   = ws + QH;       // [Q,2Q)  step8

        // 1. f_qkv = cbp_f(inp_b)              (3C, T, F)
        conv_mfma<288, 128><<<dim3(3 * 640), dim3(256), 89600, stream>>>(
            xb, W_f, b_f, g_f, be_f, m_f, v_f, a_f, fqkv, TF_, 640);
        // 2. f-attention -> fout in d_out slice (C, T, F)
        attn_mfma<0><<<dim3(T_ * (F_ / 64)), dim3(256), 102912, stream>>>(
            fqkv, fqkv + (size_t)C_ * TF_, fqkv + (size_t)2 * C_ * TF_, dob);
        // 3. foutT = transpose(fout)            (F, C, T)
        transpose_res<<<dim3(960, 8, 1), dim3(32, 8), 0, stream>>>(
            dob, nullptr, foutT, F_, C_ * T_);
        // 4. th2 = cbp_t(inp_b)                 (2C, T, F)
        conv_mfma<192, 128><<<dim3(2 * 640), dim3(256), 89600, stream>>>(
            xb, W_t, b_t, g_t, be_t, m_t, v_t, a_t, th2, TF_, 640);
        // 5. tqT = transpose(th2 q-half) -> d_out slice (fout dead)
        transpose_res<<<dim3(960, 8, 1), dim3(32, 8), 0, stream>>>(
            th2, nullptr, dob, F_, C_ * T_);
        // 6. tkT = transpose(th2 k-half)        (F, C, T)
        transpose_res<<<dim3(960, 8, 1), dim3(32, 8), 0, stream>>>(
            th2 + QH, nullptr, tkT, F_, C_ * T_);
        // 7. t-attention(Q=tqT, K=tkT, V=foutT) -> tout  (F, C, T)
        attn_mfma<1><<<dim3(F_ * (T_ / 64)), dim3(256), 123904, stream>>>(
            dob, tkT, foutT, tout);
        // 8. tmp = cbp_p(tout), groups f        (F, C, T)
        conv_mfma<96, 160><<<dim3(256 * 2), dim3(256), 102400, stream>>>(
            tout, W_p, b_p, g_p, be_p, m_p, v_p, a_p, tmp, T_, 2);
        // 9. out_b = transpose(tmp) + inp_b     (C, T, F)
        transpose_res<<<dim3(8, 960, 1), dim3(32, 8), 0, stream>>>(
            tmp, xb, dob, C_ * T_, F_);
    }
}

// Round 7
// 1205.094 us; speedup vs baseline: 30.9619x; 1.2744x over previous
//
#include <hip/hip_runtime.h>
#include <math.h>

typedef float f4 __attribute__((ext_vector_type(4)));
typedef float f2 __attribute__((ext_vector_type(2)));
typedef float f32x4 __attribute__((ext_vector_type(4)));
typedef _Float16 h8 __attribute__((ext_vector_type(8)));
typedef _Float16 h4 __attribute__((ext_vector_type(4)));

constexpr int B_ = 4, C_ = 96, T_ = 320, F_ = 256;
constexpr int TF_ = T_ * F_;          // 81920
constexpr float EPS_ = 1e-5f;

// ---------------------------------------------------------------------------
// MFMA 1x1-conv GEMM + BN + PReLU, f16 two-term split (fp32-accurate).
// ---------------------------------------------------------------------------
template<int COUT, int PT>
__global__ __launch_bounds__(256)
void conv_mfma(const float* __restrict__ x, const float* __restrict__ W,
               const float* __restrict__ bias, const float* __restrict__ gamma,
               const float* __restrict__ beta, const float* __restrict__ mean,
               const float* __restrict__ var,  const float* __restrict__ aP,
               float* __restrict__ y, int P, int ptilesPerG)
{
    constexpr int NCO = COUT / 96;
    constexpr int NN  = (PT / 16) / 2;     // N-tiles per wave (4 | 5)
    constexpr int LS  = 200;               // LDS row stride (f16 elems)
    extern __shared__ _Float16 ldsh[];
    _Float16* Xs = ldsh;                   // [PT][LS]  cols: 0-95 hi, 96-191 lo
    _Float16* Ws = ldsh + PT * LS;         // [96][LS]

    const int tid = threadIdx.x;
    const int pt  = blockIdx.x % ptilesPerG;
    const int cot = (blockIdx.x / ptilesPerG) % NCO;
    const int g   = blockIdx.x / (ptilesPerG * NCO);
    const int p0  = pt * PT;

    const float* xg = x + (size_t)g * 96 * P + p0;
    for (int e = tid; e < PT * 12; e += 256) {
        const int p = e % PT, k0 = (e / PT) * 8;
        const float* xp = xg + (size_t)k0 * P + p;
        h8 hv, lv;
#pragma unroll
        for (int j = 0; j < 8; ++j) {
            const float xv = xp[(size_t)j * P];
            const _Float16 xh = (_Float16)xv;
            hv[j] = xh;
            lv[j] = (_Float16)(xv - (float)xh);
        }
        *(h8*)&Xs[p * LS + k0]      = hv;
        *(h8*)&Xs[p * LS + 96 + k0] = lv;
    }
    const float* wg = W + (size_t)cot * 96 * 96;
    for (int e = tid; e < 96 * 24; e += 256) {
        const f4 wv = *(const f4*)&wg[e * 4];
        const int co = e / 24, k = (e % 24) * 4;
        h4 hv, lv;
#pragma unroll
        for (int j = 0; j < 4; ++j) {
            const _Float16 wh = (_Float16)wv[j];
            hv[j] = wh;
            lv[j] = (_Float16)(wv[j] - (float)wh);
        }
        *(h4*)&Ws[co * LS + k]      = hv;
        *(h4*)&Ws[co * LS + 96 + k] = lv;
    }
    __syncthreads();

    const int lane = tid & 63, wid = tid >> 6;
    const int l16 = lane & 15, lg = lane >> 4;
    const int wm = wid >> 1, wn = wid & 1;

    h8 af[3][6];
#pragma unroll
    for (int mt = 0; mt < 3; ++mt)
#pragma unroll
        for (int wk = 0; wk < 6; ++wk)
            af[mt][wk] = *(const h8*)&Ws[((wm * 3 + mt) * 16 + l16) * LS + wk * 32 + lg * 8];

    f32x4 acc[3][NN];
#pragma unroll
    for (int mt = 0; mt < 3; ++mt)
#pragma unroll
        for (int nn = 0; nn < NN; ++nn) acc[mt][nn] = (f32x4){0.f, 0.f, 0.f, 0.f};

#pragma unroll
    for (int xk = 0; xk < 6; ++xk) {             // 0-2: Xh, 3-5: Xl
        h8 bf[NN];
#pragma unroll
        for (int nn = 0; nn < NN; ++nn)
            bf[nn] = *(const h8*)&Xs[((wn * NN + nn) * 16 + l16) * LS + xk * 32 + lg * 8];
        if (xk < 3) {
#pragma unroll
            for (int mt = 0; mt < 3; ++mt)
#pragma unroll
                for (int nn = 0; nn < NN; ++nn) {
                    acc[mt][nn] = __builtin_amdgcn_mfma_f32_16x16x32_f16(
                        af[mt][xk], bf[nn], acc[mt][nn], 0, 0, 0);
                    acc[mt][nn] = __builtin_amdgcn_mfma_f32_16x16x32_f16(
                        af[mt][xk + 3], bf[nn], acc[mt][nn], 0, 0, 0);
                }
        } else {
#pragma unroll
            for (int mt = 0; mt < 3; ++mt)
#pragma unroll
                for (int nn = 0; nn < NN; ++nn)
                    acc[mt][nn] = __builtin_amdgcn_mfma_f32_16x16x32_f16(
                        af[mt][xk - 3], bf[nn], acc[mt][nn], 0, 0, 0);
        }
    }

    const float a = aP[0];
    const int cobase = cot * 96;
#pragma unroll
    for (int mt = 0; mt < 3; ++mt) {
#pragma unroll
        for (int r = 0; r < 4; ++r) {
            const int co = cobase + (wm * 3 + mt) * 16 + lg * 4 + r;
            const float sc = gamma[co] * rsqrtf(var[co] + EPS_);
            const float sh = fmaf(bias[co] - mean[co], sc, beta[co]);
            float* yr = y + ((size_t)g * COUT + co) * P + p0 + wn * NN * 16 + l16;
#pragma unroll
            for (int nn = 0; nn < NN; ++nn) {
                const float v = fmaf(acc[mt][nn][r], sc, sh);
                yr[nn * 16] = v >= 0.f ? v : a * v;
            }
        }
    }
}

// ---------------------------------------------------------------------------
// 2D transpose with optional residual add (single batch).
// ---------------------------------------------------------------------------
__global__ __launch_bounds__(256)
void transpose_res(const float* __restrict__ in, const float* __restrict__ res,
                   float* __restrict__ out, int Mo, int No)
{
    __shared__ float tile[32][33];
    const int n0 = blockIdx.x * 32, m0 = blockIdx.y * 32;
    const int tx = threadIdx.x, ty = threadIdx.y;
#pragma unroll
    for (int i = 0; i < 32; i += 8)
        tile[ty + i][tx] = in[(size_t)(n0 + ty + i) * Mo + (m0 + tx)];
    __syncthreads();
#pragma unroll
    for (int i = 0; i < 32; i += 8) {
        const size_t oidx = (size_t)(m0 + ty + i) * No + (n0 + tx);
        float v = tile[tx][ty + i];
        if (res) v += res[oidx];
        out[oidx] = v;
    }
}

// ---------------------------------------------------------------------------
// MFMA f16 fused attention v2.  S = softmax(Q^T K * scale); O = V P^T.
// MODE 0: groups t (320), NY=256, LD=TF_.  MODE 1: groups f (256), NY=320, LD=T_.
// Block = 64-row strip, 4 waves x 16 rows; grid strip-MAJOR so all strips of a
// group share an XCD (NG % 8 == 0) -> K/V fetched once per group.
// LDS: Kt[NY][104] (gather-8 b128 staging) -> V[96][NY+24] over dead Kt;
// Pw[4][16][40] per-wave P-transpose tiles (wave-private: no barriers).
// Q A-frags load direct from global (no Qt).  57.5/70 KB -> 2 blocks/CU.
// ---------------------------------------------------------------------------
template<int MODE>
__global__ __launch_bounds__(256, 2)
void attn_mfma(const float* __restrict__ Qb, const float* __restrict__ Kb,
               const float* __restrict__ Vb, float* __restrict__ Ob)
{
    constexpr int NY  = (MODE == 0) ? 256 : 320;
    constexpr int LD  = (MODE == 0) ? TF_ : T_;
    constexpr int NT  = NY / 16;           // S col-tiles per wave (16 / 20)
    constexpr int NYK = NY / 32;           // PV k-iters (8 / 10)
    constexpr int KS  = 104;               // Kt stride (f16)
    constexpr int VPS = NY + 24;           // V stride (f16): 280 / 344
    constexpr int KVH = (NY * KS > 96 * VPS) ? NY * KS : 96 * VPS;
    constexpr int NG  = (MODE == 0) ? T_ : F_;   // groups (320 / 256), %8==0
    constexpr int GOFF = (MODE == 0) ? F_ : C_ * T_;

    extern __shared__ _Float16 ldsh[];
    _Float16* KV = ldsh;                 // Kt[NY][KS] -> V[96][VPS]
    _Float16* Pw = ldsh + KVH;           // [4][16][40]

    const int strip = blockIdx.x / NG;   // strip-major: XCD = grp % 8
    const int grp   = blockIdx.x % NG;
    const int m0    = strip * 64;
    const size_t off = (size_t)grp * GOFF;
    const float* Q = Qb + off;
    const float* K = Kb + off;
    const float* V = Vb + off;
    float*       O = Ob + off;

    const int tid  = threadIdx.x;
    const int lane = tid & 63, wid = tid >> 6;
    const int l16  = lane & 15, lg = lane >> 4;
    const int mw   = wid * 16;
    const float scale = 0.10206207261596575f;   // 1/sqrt(96)

    // ---- stage Kt[y][c]: gather 8 c per y -> b128 writes, conflict-light ----
    for (int e = tid; e < NY * 12; e += 256) {
        const int yy = e % NY, k0 = (e / NY) * 8;
        const float* kp = K + (size_t)k0 * LD + yy;
        h8 hv;
#pragma unroll
        for (int j = 0; j < 8; ++j) hv[j] = (_Float16)kp[(size_t)j * LD];
        *(h8*)&KV[yy * KS + k0] = hv;
    }

    // ---- Q A-frags direct from global (row m = mw+l16, k = kk*32+lg*8+j) ----
    h8 aQ[3];
#pragma unroll
    for (int kk = 0; kk < 3; ++kk) {
        const float* qp = Q + (size_t)(kk * 32 + lg * 8) * LD + m0 + mw + l16;
#pragma unroll
        for (int j = 0; j < 8; ++j) aQ[kk][j] = (_Float16)qp[(size_t)j * LD];
    }
    __syncthreads();

    // ---- S = Q^T K ----
    f32x4 sacc[NT];
#pragma unroll
    for (int t = 0; t < NT; ++t) sacc[t] = (f32x4){0.f, 0.f, 0.f, 0.f};
#pragma unroll
    for (int kk = 0; kk < 3; ++kk) {
#pragma unroll
        for (int t = 0; t < NT; ++t) {
            const h8 bK = *(const h8*)&KV[(t * 16 + l16) * KS + kk * 32 + lg * 8];
            sacc[t] = __builtin_amdgcn_mfma_f32_16x16x32_f16(aQ[kk], bK, sacc[t], 0, 0, 0);
        }
    }

    // ---- softmax rows (scale folded into exp); sacc := normalized P ----
#pragma unroll
    for (int r = 0; r < 4; ++r) {
        float mx = sacc[0][r];
#pragma unroll
        for (int t = 1; t < NT; ++t) mx = fmaxf(mx, sacc[t][r]);
        for (int d = 1; d < 16; d <<= 1) mx = fmaxf(mx, __shfl_xor(mx, d));
        float pv[NT];
        float sum = 0.f;
#pragma unroll
        for (int t = 0; t < NT; ++t) {
            pv[t] = __expf((sacc[t][r] - mx) * scale); sum += pv[t];
        }
        for (int d = 1; d < 16; d <<= 1) sum += __shfl_xor(sum, d);
        const float inv = 1.f / sum;
#pragma unroll
        for (int t = 0; t < NT; ++t) sacc[t][r] = pv[t] * inv;
    }
    __syncthreads();    // all Kt reads done

    // ---- stage V[c][y] (f16 b128) over dead Kt ----
    constexpr int NY8 = NY / 8;
    for (int e = tid; e < 96 * NY8; e += 256) {
        const int c = e / NY8, y8 = e - c * NY8;
        const float* vp = V + (size_t)c * LD + y8 * 8;
        h8 hv;
#pragma unroll
        for (int j = 0; j < 8; ++j) hv[j] = (_Float16)vp[j];
        *(h8*)&KV[c * VPS + y8 * 8] = hv;
    }
    __syncthreads();

    // ---- O = V P^T; per-yk 32-col P chunk through wave-private Pw tile ----
    _Float16* Pme = Pw + wid * 640;      // [16][40]
    f32x4 oacc[6];
#pragma unroll
    for (int ct = 0; ct < 6; ++ct) oacc[ct] = (f32x4){0.f, 0.f, 0.f, 0.f};

#pragma unroll
    for (int yk = 0; yk < NYK; ++yk) {
#pragma unroll
        for (int h = 0; h < 2; ++h)
#pragma unroll
            for (int r = 0; r < 4; ++r)
                Pme[(lg * 4 + r) * 40 + h * 16 + l16] = (_Float16)sacc[2 * yk + h][r];
        const h8 pf = *(const h8*)&Pme[l16 * 40 + lg * 8];   // in-wave DS order
#pragma unroll
        for (int ct = 0; ct < 6; ++ct) {
            const h8 av = *(const h8*)&KV[(ct * 16 + l16) * VPS + yk * 32 + lg * 8];
            oacc[ct] = __builtin_amdgcn_mfma_f32_16x16x32_f16(av, pf, oacc[ct], 0, 0, 0);
        }
    }
#pragma unroll
    for (int ct = 0; ct < 6; ++ct)
#pragma unroll
        for (int r = 0; r < 4; ++r)
            O[(size_t)(ct * 16 + lg * 4 + r) * LD + m0 + mw + l16] = oacc[ct][r];
}

// ---------------------------------------------------------------------------
extern "C" void kernel_launch(void* const* d_in, const int* in_sizes, int n_in,
                              void* d_out, int out_size, void* d_ws, size_t ws_size,
                              hipStream_t stream)
{
    const float* inp = (const float*)d_in[0];
    const float* W_f = (const float*)d_in[1];  const float* b_f = (const float*)d_in[2];
    const float* g_f = (const float*)d_in[3];  const float* be_f = (const float*)d_in[4];
    const float* m_f = (const float*)d_in[5];  const float* v_f = (const float*)d_in[6];
    const float* a_f = (const float*)d_in[7];
    const float* W_t = (const float*)d_in[8];  const float* b_t = (const float*)d_in[9];
    const float* g_t = (const float*)d_in[10]; const float* be_t = (const float*)d_in[11];
    const float* m_t = (const float*)d_in[12]; const float* v_t = (const float*)d_in[13];
    const float* a_t = (const float*)d_in[14];
    const float* W_p = (const float*)d_in[15]; const float* b_p = (const float*)d_in[16];
    const float* g_p = (const float*)d_in[17]; const float* be_p = (const float*)d_in[18];
    const float* m_p = (const float*)d_in[19]; const float* v_p = (const float*)d_in[20];
    const float* a_p = (const float*)d_in[21];

    hipFuncSetAttribute((const void*)conv_mfma<288, 128>,
                        hipFuncAttributeMaxDynamicSharedMemorySize, 89600);
    hipFuncSetAttribute((const void*)conv_mfma<192, 128>,
                        hipFuncAttributeMaxDynamicSharedMemorySize, 89600);
    hipFuncSetAttribute((const void*)conv_mfma<96, 160>,
                        hipFuncAttributeMaxDynamicSharedMemorySize, 102400);
    hipFuncSetAttribute((const void*)attn_mfma<0>,
                        hipFuncAttributeMaxDynamicSharedMemorySize, 58880);
    hipFuncSetAttribute((const void*)attn_mfma<1>,
                        hipFuncAttributeMaxDynamicSharedMemorySize, 71680);

    // Per-batch pipeline; ws = 3 quarter-buffers (94.4 MB), d_out as scratch.
    constexpr size_t QH = (size_t)C_ * T_ * F_;   // 7,864,320 floats
    float* ws = (float*)d_ws;

    for (int b = 0; b < B_; ++b) {
        const float* xb  = inp + (size_t)b * QH;
        float*       dob = (float*)d_out + (size_t)b * QH;
        float* fqkv  = ws;            // [0,3Q)  step1 -> dead after step2
        float* foutT = ws;            // [0,Q)   step3 -> V of t-attn
        float* th2   = ws + QH;       // [Q,3Q)  step4 (192-out conv_t)
        float* tkT   = ws + QH;       // [Q,2Q)  step6
        float* tout  = ws + 2 * QH;   // [2Q,3Q) step7
        float* tmp   = ws + QH;       // [Q,2Q)  step8

        // 1. f_qkv = cbp_f(inp_b)              (3C, T, F)
        conv_mfma<288, 128><<<dim3(3 * 640), dim3(256), 89600, stream>>>(
            xb, W_f, b_f, g_f, be_f, m_f, v_f, a_f, fqkv, TF_, 640);
        // 2. f-attention -> fout in d_out slice (C, T, F)
        attn_mfma<0><<<dim3(T_ * (F_ / 64)), dim3(256), 58880, stream>>>(
            fqkv, fqkv + (size_t)C_ * TF_, fqkv + (size_t)2 * C_ * TF_, dob);
        // 3. foutT = transpose(fout)            (F, C, T)
        transpose_res<<<dim3(960, 8, 1), dim3(32, 8), 0, stream>>>(
            dob, nullptr, foutT, F_, C_ * T_);
        // 4. th2 = cbp_t(inp_b)                 (2C, T, F)
        conv_mfma<192, 128><<<dim3(2 * 640), dim3(256), 89600, stream>>>(
            xb, W_t, b_t, g_t, be_t, m_t, v_t, a_t, th2, TF_, 640);
        // 5. tqT = transpose(th2 q-half) -> d_out slice (fout dead)
        transpose_res<<<dim3(960, 8, 1), dim3(32, 8), 0, stream>>>(
            th2, nullptr, dob, F_, C_ * T_);
        // 6. tkT = transpose(th2 k-half)        (F, C, T)
        transpose_res<<<dim3(960, 8, 1), dim3(32, 8), 0, stream>>>(
            th2 + QH, nullptr, tkT, F_, C_ * T_);
        // 7. t-attention(Q=tqT, K=tkT, V=foutT) -> tout  (F, C, T)
        attn_mfma<1><<<dim3(F_ * (T_ / 64)), dim3(256), 71680, stream>>>(
            dob, tkT, foutT, tout);
        // 8. tmp = cbp_p(tout), groups f        (F, C, T)
        conv_mfma<96, 160><<<dim3(256 * 2), dim3(256), 102400, stream>>>(
            tout, W_p, b_p, g_p, be_p, m_p, v_p, a_p, tmp, T_, 2);
        // 9. out_b = transpose(tmp) + inp_b     (C, T, F)
        transpose_res<<<dim3(8, 960, 1), dim3(32, 8), 0, stream>>>(
            tmp, xb, dob, C_ * T_, F_);
    }
}

// Round 8
// 1026.700 us; speedup vs baseline: 36.3417x; 1.1738x over previous
//
#include <hip/hip_runtime.h>
#include <math.h>

typedef float f4 __attribute__((ext_vector_type(4)));
typedef float f2 __attribute__((ext_vector_type(2)));
typedef float f32x4 __attribute__((ext_vector_type(4)));
typedef _Float16 h8 __attribute__((ext_vector_type(8)));
typedef _Float16 h4 __attribute__((ext_vector_type(4)));

constexpr int B_ = 4, C_ = 96, T_ = 320, F_ = 256;
constexpr int TF_ = T_ * F_;          // 81920
constexpr float EPS_ = 1e-5f;

// ---------------------------------------------------------------------------
// MFMA 1x1-conv GEMM + BN + PReLU, f16 two-term split (fp32-accurate).
// v2: W A-frags live in REGISTERS (loaded from global/L2, hi/lo split in-reg);
// LDS holds only Xs[PT][200] -> 51.2/64 KB -> 3 (2) blocks/CU for TLP.
// ---------------------------------------------------------------------------
template<int COUT, int PT, int MINW>
__global__ __launch_bounds__(256, MINW)
void conv_mfma(const float* __restrict__ x, const float* __restrict__ W,
               const float* __restrict__ bias, const float* __restrict__ gamma,
               const float* __restrict__ beta, const float* __restrict__ mean,
               const float* __restrict__ var,  const float* __restrict__ aP,
               float* __restrict__ y, int P, int ptilesPerG)
{
    constexpr int NCO = COUT / 96;
    constexpr int NN  = (PT / 16) / 2;     // N-tiles per wave (4 | 5)
    constexpr int LS  = 200;               // LDS row stride (f16 elems)
    extern __shared__ _Float16 ldsh[];
    _Float16* Xs = ldsh;                   // [PT][LS]  cols: 0-95 hi, 96-191 lo

    const int tid = threadIdx.x;
    const int pt  = blockIdx.x % ptilesPerG;
    const int cot = (blockIdx.x / ptilesPerG) % NCO;
    const int g   = blockIdx.x / (ptilesPerG * NCO);
    const int p0  = pt * PT;

    // ---- stage X: thread gathers 8 k for fixed p (loads lane-coalesced on p)
    const float* xg = x + (size_t)g * 96 * P + p0;
    for (int e = tid; e < PT * 12; e += 256) {
        const int p = e % PT, k0 = (e / PT) * 8;
        const float* xp = xg + (size_t)k0 * P + p;
        h8 hv, lv;
#pragma unroll
        for (int j = 0; j < 8; ++j) {
            const float xv = xp[(size_t)j * P];
            const _Float16 xh = (_Float16)xv;
            hv[j] = xh;
            lv[j] = (_Float16)(xv - (float)xh);
        }
        *(h8*)&Xs[p * LS + k0]      = hv;
        *(h8*)&Xs[p * LS + 96 + k0] = lv;
    }

    const int lane = tid & 63, wid = tid >> 6;
    const int l16 = lane & 15, lg = lane >> 4;
    const int wm = wid >> 1, wn = wid & 1;       // 2x2 wave grid

    // ---- W A-frags from global (L2-resident), hi/lo split in-register ----
    // af[mt][wk]: wk 0-2 = hi(k=wk*32+lg*8+j), wk 3-5 = lo(same k)
    const float* wg = W + (size_t)cot * 96 * 96;
    h8 af[3][6];
#pragma unroll
    for (int mt = 0; mt < 3; ++mt) {
        const float* wrow = wg + (size_t)((wm * 3 + mt) * 16 + l16) * 96 + lg * 8;
#pragma unroll
        for (int kk = 0; kk < 3; ++kk) {
            const f4 w0 = *(const f4*)(wrow + kk * 32);
            const f4 w1 = *(const f4*)(wrow + kk * 32 + 4);
#pragma unroll
            for (int j = 0; j < 4; ++j) {
                const _Float16 h0 = (_Float16)w0[j];
                const _Float16 h1 = (_Float16)w1[j];
                af[mt][kk][j]     = h0;
                af[mt][kk][4 + j] = h1;
                af[mt][kk + 3][j]     = (_Float16)(w0[j] - (float)h0);
                af[mt][kk + 3][4 + j] = (_Float16)(w1[j] - (float)h1);
            }
        }
    }
    __syncthreads();

    f32x4 acc[3][NN];
#pragma unroll
    for (int mt = 0; mt < 3; ++mt)
#pragma unroll
        for (int nn = 0; nn < NN; ++nn) acc[mt][nn] = (f32x4){0.f, 0.f, 0.f, 0.f};

#pragma unroll
    for (int xk = 0; xk < 6; ++xk) {             // 0-2: Xh, 3-5: Xl
        h8 bf[NN];
#pragma unroll
        for (int nn = 0; nn < NN; ++nn)
            bf[nn] = *(const h8*)&Xs[((wn * NN + nn) * 16 + l16) * LS + xk * 32 + lg * 8];
        if (xk < 3) {
#pragma unroll
            for (int mt = 0; mt < 3; ++mt)
#pragma unroll
                for (int nn = 0; nn < NN; ++nn) {
                    acc[mt][nn] = __builtin_amdgcn_mfma_f32_16x16x32_f16(
                        af[mt][xk], bf[nn], acc[mt][nn], 0, 0, 0);       // xh*wh
                    acc[mt][nn] = __builtin_amdgcn_mfma_f32_16x16x32_f16(
                        af[mt][xk + 3], bf[nn], acc[mt][nn], 0, 0, 0);   // xh*wl
                }
        } else {
#pragma unroll
            for (int mt = 0; mt < 3; ++mt)
#pragma unroll
                for (int nn = 0; nn < NN; ++nn)
                    acc[mt][nn] = __builtin_amdgcn_mfma_f32_16x16x32_f16(
                        af[mt][xk - 3], bf[nn], acc[mt][nn], 0, 0, 0);   // xl*wh
        }
    }

    // ---- BN + PReLU epilogue; D: row co = lg*4+r (within Mtile), col p = l16
    const float a = aP[0];
    const int cobase = cot * 96;
#pragma unroll
    for (int mt = 0; mt < 3; ++mt) {
#pragma unroll
        for (int r = 0; r < 4; ++r) {
            const int co = cobase + (wm * 3 + mt) * 16 + lg * 4 + r;
            const float sc = gamma[co] * rsqrtf(var[co] + EPS_);
            const float sh = fmaf(bias[co] - mean[co], sc, beta[co]);
            float* yr = y + ((size_t)g * COUT + co) * P + p0 + wn * NN * 16 + l16;
#pragma unroll
            for (int nn = 0; nn < NN; ++nn) {
                const float v = fmaf(acc[mt][nn][r], sc, sh);
                yr[nn * 16] = v >= 0.f ? v : a * v;
            }
        }
    }
}

// ---------------------------------------------------------------------------
// 2D transpose with optional residual add (single batch).
// ---------------------------------------------------------------------------
__global__ __launch_bounds__(256)
void transpose_res(const float* __restrict__ in, const float* __restrict__ res,
                   float* __restrict__ out, int Mo, int No)
{
    __shared__ float tile[32][33];
    const int n0 = blockIdx.x * 32, m0 = blockIdx.y * 32;
    const int tx = threadIdx.x, ty = threadIdx.y;
#pragma unroll
    for (int i = 0; i < 32; i += 8)
        tile[ty + i][tx] = in[(size_t)(n0 + ty + i) * Mo + (m0 + tx)];
    __syncthreads();
#pragma unroll
    for (int i = 0; i < 32; i += 8) {
        const size_t oidx = (size_t)(m0 + ty + i) * No + (n0 + tx);
        float v = tile[tx][ty + i];
        if (res) v += res[oidx];
        out[oidx] = v;
    }
}

// ---------------------------------------------------------------------------
// MFMA f16 fused attention v2.  S = softmax(Q^T K * scale); O = V P^T.
// MODE 0: groups t (320), NY=256, LD=TF_.  MODE 1: groups f (256), NY=320, LD=T_.
// Strip-major grid (XCD = grp % 8); Kt gather-8 staging; per-wave P tiles;
// Q A-frags direct from global.  57.5/70 KB LDS -> 2 blocks/CU.
// ---------------------------------------------------------------------------
template<int MODE>
__global__ __launch_bounds__(256, 2)
void attn_mfma(const float* __restrict__ Qb, const float* __restrict__ Kb,
               const float* __restrict__ Vb, float* __restrict__ Ob)
{
    constexpr int NY  = (MODE == 0) ? 256 : 320;
    constexpr int LD  = (MODE == 0) ? TF_ : T_;
    constexpr int NT  = NY / 16;
    constexpr int NYK = NY / 32;
    constexpr int KS  = 104;
    constexpr int VPS = NY + 24;
    constexpr int KVH = (NY * KS > 96 * VPS) ? NY * KS : 96 * VPS;
    constexpr int NG  = (MODE == 0) ? T_ : F_;
    constexpr int GOFF = (MODE == 0) ? F_ : C_ * T_;

    extern __shared__ _Float16 ldsh[];
    _Float16* KV = ldsh;                 // Kt[NY][KS] -> V[96][VPS]
    _Float16* Pw = ldsh + KVH;           // [4][16][40]

    const int strip = blockIdx.x / NG;
    const int grp   = blockIdx.x % NG;
    const int m0    = strip * 64;
    const size_t off = (size_t)grp * GOFF;
    const float* Q = Qb + off;
    const float* K = Kb + off;
    const float* V = Vb + off;
    float*       O = Ob + off;

    const int tid  = threadIdx.x;
    const int lane = tid & 63, wid = tid >> 6;
    const int l16  = lane & 15, lg = lane >> 4;
    const int mw   = wid * 16;
    const float scale = 0.10206207261596575f;   // 1/sqrt(96)

    for (int e = tid; e < NY * 12; e += 256) {
        const int yy = e % NY, k0 = (e / NY) * 8;
        const float* kp = K + (size_t)k0 * LD + yy;
        h8 hv;
#pragma unroll
        for (int j = 0; j < 8; ++j) hv[j] = (_Float16)kp[(size_t)j * LD];
        *(h8*)&KV[yy * KS + k0] = hv;
    }

    h8 aQ[3];
#pragma unroll
    for (int kk = 0; kk < 3; ++kk) {
        const float* qp = Q + (size_t)(kk * 32 + lg * 8) * LD + m0 + mw + l16;
#pragma unroll
        for (int j = 0; j < 8; ++j) aQ[kk][j] = (_Float16)qp[(size_t)j * LD];
    }
    __syncthreads();

    f32x4 sacc[NT];
#pragma unroll
    for (int t = 0; t < NT; ++t) sacc[t] = (f32x4){0.f, 0.f, 0.f, 0.f};
#pragma unroll
    for (int kk = 0; kk < 3; ++kk) {
#pragma unroll
        for (int t = 0; t < NT; ++t) {
            const h8 bK = *(const h8*)&KV[(t * 16 + l16) * KS + kk * 32 + lg * 8];
            sacc[t] = __builtin_amdgcn_mfma_f32_16x16x32_f16(aQ[kk], bK, sacc[t], 0, 0, 0);
        }
    }

#pragma unroll
    for (int r = 0; r < 4; ++r) {
        float mx = sacc[0][r];
#pragma unroll
        for (int t = 1; t < NT; ++t) mx = fmaxf(mx, sacc[t][r]);
        for (int d = 1; d < 16; d <<= 1) mx = fmaxf(mx, __shfl_xor(mx, d));
        float pv[NT];
        float sum = 0.f;
#pragma unroll
        for (int t = 0; t < NT; ++t) {
            pv[t] = __expf((sacc[t][r] - mx) * scale); sum += pv[t];
        }
        for (int d = 1; d < 16; d <<= 1) sum += __shfl_xor(sum, d);
        const float inv = 1.f / sum;
#pragma unroll
        for (int t = 0; t < NT; ++t) sacc[t][r] = pv[t] * inv;
    }
    __syncthreads();

    constexpr int NY8 = NY / 8;
    for (int e = tid; e < 96 * NY8; e += 256) {
        const int c = e / NY8, y8 = e - c * NY8;
        const float* vp = V + (size_t)c * LD + y8 * 8;
        h8 hv;
#pragma unroll
        for (int j = 0; j < 8; ++j) hv[j] = (_Float16)vp[j];
        *(h8*)&KV[c * VPS + y8 * 8] = hv;
    }
    __syncthreads();

    _Float16* Pme = Pw + wid * 640;      // [16][40]
    f32x4 oacc[6];
#pragma unroll
    for (int ct = 0; ct < 6; ++ct) oacc[ct] = (f32x4){0.f, 0.f, 0.f, 0.f};

#pragma unroll
    for (int yk = 0; yk < NYK; ++yk) {
#pragma unroll
        for (int h = 0; h < 2; ++h)
#pragma unroll
            for (int r = 0; r < 4; ++r)
                Pme[(lg * 4 + r) * 40 + h * 16 + l16] = (_Float16)sacc[2 * yk + h][r];
        const h8 pf = *(const h8*)&Pme[l16 * 40 + lg * 8];   // in-wave DS order
#pragma unroll
        for (int ct = 0; ct < 6; ++ct) {
            const h8 av = *(const h8*)&KV[(ct * 16 + l16) * VPS + yk * 32 + lg * 8];
            oacc[ct] = __builtin_amdgcn_mfma_f32_16x16x32_f16(av, pf, oacc[ct], 0, 0, 0);
        }
    }
#pragma unroll
    for (int ct = 0; ct < 6; ++ct)
#pragma unroll
        for (int r = 0; r < 4; ++r)
            O[(size_t)(ct * 16 + lg * 4 + r) * LD + m0 + mw + l16] = oacc[ct][r];
}

// ---------------------------------------------------------------------------
extern "C" void kernel_launch(void* const* d_in, const int* in_sizes, int n_in,
                              void* d_out, int out_size, void* d_ws, size_t ws_size,
                              hipStream_t stream)
{
    const float* inp = (const float*)d_in[0];
    const float* W_f = (const float*)d_in[1];  const float* b_f = (const float*)d_in[2];
    const float* g_f = (const float*)d_in[3];  const float* be_f = (const float*)d_in[4];
    const float* m_f = (const float*)d_in[5];  const float* v_f = (const float*)d_in[6];
    const float* a_f = (const float*)d_in[7];
    const float* W_t = (const float*)d_in[8];  const float* b_t = (const float*)d_in[9];
    const float* g_t = (const float*)d_in[10]; const float* be_t = (const float*)d_in[11];
    const float* m_t = (const float*)d_in[12]; const float* v_t = (const float*)d_in[13];
    const float* a_t = (const float*)d_in[14];
    const float* W_p = (const float*)d_in[15]; const float* b_p = (const float*)d_in[16];
    const float* g_p = (const float*)d_in[17]; const float* be_p = (const float*)d_in[18];
    const float* m_p = (const float*)d_in[19]; const float* v_p = (const float*)d_in[20];
    const float* a_p = (const float*)d_in[21];

    hipFuncSetAttribute((const void*)conv_mfma<288, 128, 3>,
                        hipFuncAttributeMaxDynamicSharedMemorySize, 51200);
    hipFuncSetAttribute((const void*)conv_mfma<192, 128, 3>,
                        hipFuncAttributeMaxDynamicSharedMemorySize, 51200);
    hipFuncSetAttribute((const void*)conv_mfma<96, 160, 2>,
                        hipFuncAttributeMaxDynamicSharedMemorySize, 64000);
    hipFuncSetAttribute((const void*)attn_mfma<0>,
                        hipFuncAttributeMaxDynamicSharedMemorySize, 58880);
    hipFuncSetAttribute((const void*)attn_mfma<1>,
                        hipFuncAttributeMaxDynamicSharedMemorySize, 71680);

    // Per-batch pipeline; ws = 3 quarter-buffers (94.4 MB), d_out as scratch.
    constexpr size_t QH = (size_t)C_ * T_ * F_;   // 7,864,320 floats
    float* ws = (float*)d_ws;

    for (int b = 0; b < B_; ++b) {
        const float* xb  = inp + (size_t)b * QH;
        float*       dob = (float*)d_out + (size_t)b * QH;
        float* fqkv  = ws;            // [0,3Q)  step1 -> dead after step2
        float* foutT = ws;            // [0,Q)   step3 -> V of t-attn
        float* th2   = ws + QH;       // [Q,3Q)  step4 (192-out conv_t)
        float* tkT   = ws + QH;       // [Q,2Q)  step6
        float* tout  = ws + 2 * QH;   // [2Q,3Q) step7
        float* tmp   = ws + QH;       // [Q,2Q)  step8

        // 1. f_qkv = cbp_f(inp_b)              (3C, T, F)
        conv_mfma<288, 128, 3><<<dim3(3 * 640), dim3(256), 51200, stream>>>(
            xb, W_f, b_f, g_f, be_f, m_f, v_f, a_f, fqkv, TF_, 640);
        // 2. f-attention -> fout in d_out slice (C, T, F)
        attn_mfma<0><<<dim3(T_ * (F_ / 64)), dim3(256), 58880, stream>>>(
            fqkv, fqkv + (size_t)C_ * TF_, fqkv + (size_t)2 * C_ * TF_, dob);
        // 3. foutT = transpose(fout)            (F, C, T)
        transpose_res<<<dim3(960, 8, 1), dim3(32, 8), 0, stream>>>(
            dob, nullptr, foutT, F_, C_ * T_);
        // 4. th2 = cbp_t(inp_b)                 (2C, T, F)
        conv_mfma<192, 128, 3><<<dim3(2 * 640), dim3(256), 51200, stream>>>(
            xb, W_t, b_t, g_t, be_t, m_t, v_t, a_t, th2, TF_, 640);
        // 5. tqT = transpose(th2 q-half) -> d_out slice (fout dead)
        transpose_res<<<dim3(960, 8, 1), dim3(32, 8), 0, stream>>>(
            th2, nullptr, dob, F_, C_ * T_);
        // 6. tkT = transpose(th2 k-half)        (F, C, T)
        transpose_res<<<dim3(960, 8, 1), dim3(32, 8), 0, stream>>>(
            th2 + QH, nullptr, tkT, F_, C_ * T_);
        // 7. t-attention(Q=tqT, K=tkT, V=foutT) -> tout  (F, C, T)
        attn_mfma<1><<<dim3(F_ * (T_ / 64)), dim3(256), 71680, stream>>>(
            dob, tkT, foutT, tout);
        // 8. tmp = cbp_p(tout), groups f        (F, C, T)
        conv_mfma<96, 160, 2><<<dim3(256 * 2), dim3(256), 64000, stream>>>(
            tout, W_p, b_p, g_p, be_p, m_p, v_p, a_p, tmp, T_, 2);
        // 9. out_b = transpose(tmp) + inp_b     (C, T, F)
        transpose_res<<<dim3(8, 960, 1), dim3(32, 8), 0, stream>>>(
            tmp, xb, dob, C_ * T_, F_);
    }
}

// Round 9
// 889.380 us; speedup vs baseline: 41.9528x; 1.1544x over previous
//
#include <hip/hip_runtime.h>
#include <math.h>

typedef float f4 __attribute__((ext_vector_type(4)));
typedef float f32x4 __attribute__((ext_vector_type(4)));
typedef _Float16 h8 __attribute__((ext_vector_type(8)));

constexpr int B_ = 4, C_ = 96, T_ = 320, F_ = 256;
constexpr int TF_ = T_ * F_;          // 81920
constexpr float EPS_ = 1e-5f;

// ---------------------------------------------------------------------------
// MFMA 1x1-conv GEMM + BN + PReLU.
// XT=float:    f16 two-term split (x=xh+xl, w=wh+wl; drop xl*wl) - fp32-accurate.
// XT=_Float16: input already f16 -> xh only (2 MFMAs/step), half X-LDS.
// YT: output type (f16 intermediates).  W A-frags in registers from L2.
// ---------------------------------------------------------------------------
template<typename XT, typename YT, int COUT, int PT, int MINW>
__global__ __launch_bounds__(256, MINW)
void conv_mfma(const XT* __restrict__ x, const float* __restrict__ W,
               const float* __restrict__ bias, const float* __restrict__ gamma,
               const float* __restrict__ beta, const float* __restrict__ mean,
               const float* __restrict__ var,  const float* __restrict__ aP,
               YT* __restrict__ y, int P, int ptilesPerG)
{
    constexpr bool XF16 = (sizeof(XT) == 2);
    constexpr int NCO = COUT / 96;
    constexpr int NN  = (PT / 16) / 2;     // N-tiles per wave (4 | 5)
    constexpr int LS  = XF16 ? 104 : 200;  // LDS row stride (f16 elems)
    extern __shared__ _Float16 ldsh[];
    _Float16* Xs = ldsh;                   // [PT][LS]; f32: 0-95 hi, 96-191 lo

    const int tid = threadIdx.x;
    const int pt  = blockIdx.x % ptilesPerG;
    const int cot = (blockIdx.x / ptilesPerG) % NCO;
    const int g   = blockIdx.x / (ptilesPerG * NCO);
    const int p0  = pt * PT;

    // ---- stage X: thread gathers 8 k for fixed p (loads lane-coalesced on p)
    const XT* xg = x + (size_t)g * 96 * P + p0;
    for (int e = tid; e < PT * 12; e += 256) {
        const int p = e % PT, k0 = (e / PT) * 8;
        const XT* xp = xg + (size_t)k0 * P + p;
        if constexpr (XF16) {
            h8 hv;
#pragma unroll
            for (int j = 0; j < 8; ++j) hv[j] = xp[(size_t)j * P];
            *(h8*)&Xs[p * LS + k0] = hv;
        } else {
            h8 hv, lv;
#pragma unroll
            for (int j = 0; j < 8; ++j) {
                const float xv = xp[(size_t)j * P];
                const _Float16 xh = (_Float16)xv;
                hv[j] = xh;
                lv[j] = (_Float16)(xv - (float)xh);
            }
            *(h8*)&Xs[p * LS + k0]      = hv;
            *(h8*)&Xs[p * LS + 96 + k0] = lv;
        }
    }

    const int lane = tid & 63, wid = tid >> 6;
    const int l16 = lane & 15, lg = lane >> 4;
    const int wm = wid >> 1, wn = wid & 1;       // 2x2 wave grid

    // ---- W A-frags from global (L2-resident), hi/lo split in-register ----
    const float* wg = W + (size_t)cot * 96 * 96;
    h8 af[3][6];
#pragma unroll
    for (int mt = 0; mt < 3; ++mt) {
        const float* wrow = wg + (size_t)((wm * 3 + mt) * 16 + l16) * 96 + lg * 8;
#pragma unroll
        for (int kk = 0; kk < 3; ++kk) {
            const f4 w0 = *(const f4*)(wrow + kk * 32);
            const f4 w1 = *(const f4*)(wrow + kk * 32 + 4);
#pragma unroll
            for (int j = 0; j < 4; ++j) {
                const _Float16 h0 = (_Float16)w0[j];
                const _Float16 h1 = (_Float16)w1[j];
                af[mt][kk][j]     = h0;
                af[mt][kk][4 + j] = h1;
                af[mt][kk + 3][j]     = (_Float16)(w0[j] - (float)h0);
                af[mt][kk + 3][4 + j] = (_Float16)(w1[j] - (float)h1);
            }
        }
    }
    __syncthreads();

    f32x4 acc[3][NN];
#pragma unroll
    for (int mt = 0; mt < 3; ++mt)
#pragma unroll
        for (int nn = 0; nn < NN; ++nn) acc[mt][nn] = (f32x4){0.f, 0.f, 0.f, 0.f};

    constexpr int XKMAX = XF16 ? 3 : 6;
#pragma unroll
    for (int xk = 0; xk < XKMAX; ++xk) {         // 0-2: Xh, 3-5: Xl (f32 only)
        h8 bf[NN];
#pragma unroll
        for (int nn = 0; nn < NN; ++nn)
            bf[nn] = *(const h8*)&Xs[((wn * NN + nn) * 16 + l16) * LS + xk * 32 + lg * 8];
        if (xk < 3) {
#pragma unroll
            for (int mt = 0; mt < 3; ++mt)
#pragma unroll
                for (int nn = 0; nn < NN; ++nn) {
                    acc[mt][nn] = __builtin_amdgcn_mfma_f32_16x16x32_f16(
                        af[mt][xk], bf[nn], acc[mt][nn], 0, 0, 0);       // xh*wh
                    acc[mt][nn] = __builtin_amdgcn_mfma_f32_16x16x32_f16(
                        af[mt][xk + 3], bf[nn], acc[mt][nn], 0, 0, 0);   // xh*wl
                }
        } else {
#pragma unroll
            for (int mt = 0; mt < 3; ++mt)
#pragma unroll
                for (int nn = 0; nn < NN; ++nn)
                    acc[mt][nn] = __builtin_amdgcn_mfma_f32_16x16x32_f16(
                        af[mt][xk - 3], bf[nn], acc[mt][nn], 0, 0, 0);   // xl*wh
        }
    }

    // ---- BN + PReLU epilogue (fp32), store YT ----
    const float a = aP[0];
    const int cobase = cot * 96;
#pragma unroll
    for (int mt = 0; mt < 3; ++mt) {
#pragma unroll
        for (int r = 0; r < 4; ++r) {
            const int co = cobase + (wm * 3 + mt) * 16 + lg * 4 + r;
            const float sc = gamma[co] * rsqrtf(var[co] + EPS_);
            const float sh = fmaf(bias[co] - mean[co], sc, beta[co]);
            YT* yr = y + ((size_t)g * COUT + co) * P + p0 + wn * NN * 16 + l16;
#pragma unroll
            for (int nn = 0; nn < NN; ++nn) {
                const float v = fmaf(acc[mt][nn][r], sc, sh);
                yr[nn * 16] = (YT)(v >= 0.f ? v : a * v);
            }
        }
    }
}

// ---------------------------------------------------------------------------
// f16 -> f16 2D transpose (single batch).  out[m][n] = in[n][m].
// in: (No, Mo)  out: (Mo, No).  tile[32][34]: stride 17 banks, conflict-free.
// ---------------------------------------------------------------------------
__global__ __launch_bounds__(256)
void transpose_h(const _Float16* __restrict__ in, _Float16* __restrict__ out,
                 int Mo, int No)
{
    __shared__ _Float16 tile[32][34];
    const int n0 = blockIdx.x * 32, m0 = blockIdx.y * 32;
    const int tx = threadIdx.x, ty = threadIdx.y;
#pragma unroll
    for (int i = 0; i < 32; i += 8)
        tile[ty + i][tx] = in[(size_t)(n0 + ty + i) * Mo + (m0 + tx)];
    __syncthreads();
#pragma unroll
    for (int i = 0; i < 32; i += 8)
        out[(size_t)(m0 + ty + i) * No + (n0 + tx)] = tile[tx][ty + i];
}

// ---------------------------------------------------------------------------
// f16 in + f32 residual -> f32 out transpose (final step).
// ---------------------------------------------------------------------------
__global__ __launch_bounds__(256)
void transpose_hf_res(const _Float16* __restrict__ in, const float* __restrict__ res,
                      float* __restrict__ out, int Mo, int No)
{
    __shared__ _Float16 tile[32][34];
    const int n0 = blockIdx.x * 32, m0 = blockIdx.y * 32;
    const int tx = threadIdx.x, ty = threadIdx.y;
#pragma unroll
    for (int i = 0; i < 32; i += 8)
        tile[ty + i][tx] = in[(size_t)(n0 + ty + i) * Mo + (m0 + tx)];
    __syncthreads();
#pragma unroll
    for (int i = 0; i < 32; i += 8) {
        const size_t oidx = (size_t)(m0 + ty + i) * No + (n0 + tx);
        out[oidx] = (float)tile[tx][ty + i] + res[oidx];
    }
}

// ---------------------------------------------------------------------------
// MFMA f16 fused attention v3 — all-f16 I/O.  S = softmax(Q^T K * scale); O = V P^T.
// MODE 0: groups t (320), NY=256, LD=TF_.  MODE 1: groups f (256), NY=320, LD=T_.
// Strip-major grid (XCD = grp % 8); Kt gather-8 staging; per-wave P tiles;
// Q A-frags direct from global.  57.5/70 KB LDS -> 2 blocks/CU.
// ---------------------------------------------------------------------------
template<int MODE>
__global__ __launch_bounds__(256, 2)
void attn_mfma(const _Float16* __restrict__ Qb, const _Float16* __restrict__ Kb,
               const _Float16* __restrict__ Vb, _Float16* __restrict__ Ob)
{
    constexpr int NY  = (MODE == 0) ? 256 : 320;
    constexpr int LD  = (MODE == 0) ? TF_ : T_;
    constexpr int NT  = NY / 16;
    constexpr int NYK = NY / 32;
    constexpr int KS  = 104;
    constexpr int VPS = NY + 24;
    constexpr int KVH = (NY * KS > 96 * VPS) ? NY * KS : 96 * VPS;
    constexpr int NG  = (MODE == 0) ? T_ : F_;
    constexpr int GOFF = (MODE == 0) ? F_ : C_ * T_;

    extern __shared__ _Float16 ldsh[];
    _Float16* KV = ldsh;                 // Kt[NY][KS] -> V[96][VPS]
    _Float16* Pw = ldsh + KVH;           // [4][16][40]

    const int strip = blockIdx.x / NG;
    const int grp   = blockIdx.x % NG;
    const int m0    = strip * 64;
    const size_t off = (size_t)grp * GOFF;
    const _Float16* Q = Qb + off;
    const _Float16* K = Kb + off;
    const _Float16* V = Vb + off;
    _Float16*       O = Ob + off;

    const int tid  = threadIdx.x;
    const int lane = tid & 63, wid = tid >> 6;
    const int l16  = lane & 15, lg = lane >> 4;
    const int mw   = wid * 16;
    const float scale = 0.10206207261596575f;   // 1/sqrt(96)

    // ---- stage Kt[y][c]: gather 8 c per y; lanes coalesced along y ----
    for (int e = tid; e < NY * 12; e += 256) {
        const int yy = e % NY, k0 = (e / NY) * 8;
        const _Float16* kp = K + (size_t)k0 * LD + yy;
        h8 hv;
#pragma unroll
        for (int j = 0; j < 8; ++j) hv[j] = kp[(size_t)j * LD];
        *(h8*)&KV[yy * KS + k0] = hv;
    }

    // ---- Q A-frags direct from global ----
    h8 aQ[3];
#pragma unroll
    for (int kk = 0; kk < 3; ++kk) {
        const _Float16* qp = Q + (size_t)(kk * 32 + lg * 8) * LD + m0 + mw + l16;
#pragma unroll
        for (int j = 0; j < 8; ++j) aQ[kk][j] = qp[(size_t)j * LD];
    }
    __syncthreads();

    // ---- S = Q^T K ----
    f32x4 sacc[NT];
#pragma unroll
    for (int t = 0; t < NT; ++t) sacc[t] = (f32x4){0.f, 0.f, 0.f, 0.f};
#pragma unroll
    for (int kk = 0; kk < 3; ++kk) {
#pragma unroll
        for (int t = 0; t < NT; ++t) {
            const h8 bK = *(const h8*)&KV[(t * 16 + l16) * KS + kk * 32 + lg * 8];
            sacc[t] = __builtin_amdgcn_mfma_f32_16x16x32_f16(aQ[kk], bK, sacc[t], 0, 0, 0);
        }
    }

    // ---- softmax (fp32, scale folded into exp); sacc := normalized P ----
#pragma unroll
    for (int r = 0; r < 4; ++r) {
        float mx = sacc[0][r];
#pragma unroll
        for (int t = 1; t < NT; ++t) mx = fmaxf(mx, sacc[t][r]);
        for (int d = 1; d < 16; d <<= 1) mx = fmaxf(mx, __shfl_xor(mx, d));
        float pv[NT];
        float sum = 0.f;
#pragma unroll
        for (int t = 0; t < NT; ++t) {
            pv[t] = __expf((sacc[t][r] - mx) * scale); sum += pv[t];
        }
        for (int d = 1; d < 16; d <<= 1) sum += __shfl_xor(sum, d);
        const float inv = 1.f / sum;
#pragma unroll
        for (int t = 0; t < NT; ++t) sacc[t][r] = pv[t] * inv;
    }
    __syncthreads();

    // ---- stage V[c][y] over dead Kt: contiguous h8 copies ----
    constexpr int NY8 = NY / 8;
    for (int e = tid; e < 96 * NY8; e += 256) {
        const int c = e / NY8, y8 = e - c * NY8;
        *(h8*)&KV[c * VPS + y8 * 8] = *(const h8*)(V + (size_t)c * LD + y8 * 8);
    }
    __syncthreads();

    // ---- O = V P^T via per-wave P-transpose tiles ----
    _Float16* Pme = Pw + wid * 640;      // [16][40]
    f32x4 oacc[6];
#pragma unroll
    for (int ct = 0; ct < 6; ++ct) oacc[ct] = (f32x4){0.f, 0.f, 0.f, 0.f};

#pragma unroll
    for (int yk = 0; yk < NYK; ++yk) {
#pragma unroll
        for (int h = 0; h < 2; ++h)
#pragma unroll
            for (int r = 0; r < 4; ++r)
                Pme[(lg * 4 + r) * 40 + h * 16 + l16] = (_Float16)sacc[2 * yk + h][r];
        const h8 pf = *(const h8*)&Pme[l16 * 40 + lg * 8];   // in-wave DS order
#pragma unroll
        for (int ct = 0; ct < 6; ++ct) {
            const h8 av = *(const h8*)&KV[(ct * 16 + l16) * VPS + yk * 32 + lg * 8];
            oacc[ct] = __builtin_amdgcn_mfma_f32_16x16x32_f16(av, pf, oacc[ct], 0, 0, 0);
        }
    }
#pragma unroll
    for (int ct = 0; ct < 6; ++ct)
#pragma unroll
        for (int r = 0; r < 4; ++r)
            O[(size_t)(ct * 16 + lg * 4 + r) * LD + m0 + mw + l16] = (_Float16)oacc[ct][r];
}

// ---------------------------------------------------------------------------
extern "C" void kernel_launch(void* const* d_in, const int* in_sizes, int n_in,
                              void* d_out, int out_size, void* d_ws, size_t ws_size,
                              hipStream_t stream)
{
    const float* inp = (const float*)d_in[0];
    const float* W_f = (const float*)d_in[1];  const float* b_f = (const float*)d_in[2];
    const float* g_f = (const float*)d_in[3];  const float* be_f = (const float*)d_in[4];
    const float* m_f = (const float*)d_in[5];  const float* v_f = (const float*)d_in[6];
    const float* a_f = (const float*)d_in[7];
    const float* W_t = (const float*)d_in[8];  const float* b_t = (const float*)d_in[9];
    const float* g_t = (const float*)d_in[10]; const float* be_t = (const float*)d_in[11];
    const float* m_t = (const float*)d_in[12]; const float* v_t = (const float*)d_in[13];
    const float* a_t = (const float*)d_in[14];
    const float* W_p = (const float*)d_in[15]; const float* b_p = (const float*)d_in[16];
    const float* g_p = (const float*)d_in[17]; const float* be_p = (const float*)d_in[18];
    const float* m_p = (const float*)d_in[19]; const float* v_p = (const float*)d_in[20];
    const float* a_p = (const float*)d_in[21];

    hipFuncSetAttribute((const void*)conv_mfma<float, _Float16, 288, 128, 3>,
                        hipFuncAttributeMaxDynamicSharedMemorySize, 51200);
    hipFuncSetAttribute((const void*)conv_mfma<float, _Float16, 192, 128, 3>,
                        hipFuncAttributeMaxDynamicSharedMemorySize, 51200);
    hipFuncSetAttribute((const void*)conv_mfma<_Float16, _Float16, 96, 160, 3>,
                        hipFuncAttributeMaxDynamicSharedMemorySize, 33280);
    hipFuncSetAttribute((const void*)attn_mfma<0>,
                        hipFuncAttributeMaxDynamicSharedMemorySize, 58880);
    hipFuncSetAttribute((const void*)attn_mfma<1>,
                        hipFuncAttributeMaxDynamicSharedMemorySize, 71680);

    // Per-batch pipeline; all intermediates f16.  ws peak = 6 half-buffers
    // (94.4 MB); d_out batch slice doubles as f16 scratch (fout, then tqT).
    constexpr size_t QH  = (size_t)C_ * T_ * F_;   // elems per (C,T,F) buffer
    constexpr size_t QB2 = QH * 2;                 // bytes of an f16 buffer
    char* wsb = (char*)d_ws;

    for (int b = 0; b < B_; ++b) {
        const float* xb  = inp + (size_t)b * QH;
        float*       dob = (float*)d_out + (size_t)b * QH;
        _Float16* fqkv  = (_Float16*)wsb;              // [0,3)   step1 -> dead @2
        _Float16* foutT = (_Float16*)(wsb + 3 * QB2);  // [3,4)   step3 -> attn1 V
        _Float16* th2   = (_Float16*)(wsb + 4 * QB2);  // [4,6)   step4 -> dead @6
        _Float16* tkT   = (_Float16*)wsb;              // [0,1)   step6 (fqkv dead)
        _Float16* tout  = (_Float16*)(wsb + QB2);      // [1,2)   step7
        _Float16* tmp   = (_Float16*)(wsb + 2 * QB2);  // [2,3)   step8
        _Float16* fout  = (_Float16*)dob;              // steps 2-3
        _Float16* tqT   = (_Float16*)dob;              // steps 5-7 (fout dead)

        // 1. f_qkv = cbp_f(inp_b)              (3C, T, F) f16
        conv_mfma<float, _Float16, 288, 128, 3><<<dim3(3 * 640), dim3(256), 51200, stream>>>(
            xb, W_f, b_f, g_f, be_f, m_f, v_f, a_f, fqkv, TF_, 640);
        // 2. f-attention -> fout               (C, T, F) f16
        attn_mfma<0><<<dim3(T_ * (F_ / 64)), dim3(256), 58880, stream>>>(
            fqkv, fqkv + (size_t)C_ * TF_, fqkv + (size_t)2 * C_ * TF_, fout);
        // 3. foutT = transpose(fout)           (F, C, T) f16
        transpose_h<<<dim3(960, 8, 1), dim3(32, 8), 0, stream>>>(
            fout, foutT, F_, C_ * T_);
        // 4. th2 = cbp_t(inp_b)                (2C, T, F) f16
        conv_mfma<float, _Float16, 192, 128, 3><<<dim3(2 * 640), dim3(256), 51200, stream>>>(
            xb, W_t, b_t, g_t, be_t, m_t, v_t, a_t, th2, TF_, 640);
        // 5. tqT = transpose(th2 q-half)       (F, C, T) f16 -> dob (fout dead)
        transpose_h<<<dim3(960, 8, 1), dim3(32, 8), 0, stream>>>(
            th2, tqT, F_, C_ * T_);
        // 6. tkT = transpose(th2 k-half)       (F, C, T) f16
        transpose_h<<<dim3(960, 8, 1), dim3(32, 8), 0, stream>>>(
            th2 + (size_t)C_ * TF_, tkT, F_, C_ * T_);
        // 7. t-attention(Q=tqT,K=tkT,V=foutT) -> tout   (F, C, T) f16
        attn_mfma<1><<<dim3(F_ * (T_ / 64)), dim3(256), 71680, stream>>>(
            tqT, tkT, foutT, tout);
        // 8. tmp = cbp_p(tout), groups f       (F, C, T) f16
        conv_mfma<_Float16, _Float16, 96, 160, 3><<<dim3(256 * 2), dim3(256), 33280, stream>>>(
            tout, W_p, b_p, g_p, be_p, m_p, v_p, a_p, tmp, T_, 2);
        // 9. out_b = transpose(tmp) + inp_b    (C, T, F) f32
        transpose_hf_res<<<dim3(8, 960, 1), dim3(32, 8), 0, stream>>>(
            tmp, xb, dob, C_ * T_, F_);
    }
}

// Round 10
// 853.619 us; speedup vs baseline: 43.7104x; 1.0419x over previous
//
#include <hip/hip_runtime.h>
#include <math.h>

typedef float f4 __attribute__((ext_vector_type(4)));
typedef float f32x4 __attribute__((ext_vector_type(4)));
typedef _Float16 h8 __attribute__((ext_vector_type(8)));

constexpr int B_ = 4, C_ = 96, T_ = 320, F_ = 256;
constexpr int TF_ = T_ * F_;          // 81920
constexpr float EPS_ = 1e-5f;

// ---------------------------------------------------------------------------
// MFMA 1x1-conv GEMM + BN + PReLU.  blockIdx.y = batch-in-pair (strides bsx/bsy).
// XT=float:    f16 two-term split (fp32-accurate).  XT=_Float16: xh only.
// PT=64 for f32 path -> 25.6 KB LDS -> ~6 blocks/CU (VGPR ~84: 504/SIMD fits).
// ---------------------------------------------------------------------------
template<typename XT, typename YT, int COUT, int PT, int MINW>
__global__ __launch_bounds__(256, MINW)
void conv_mfma(const XT* __restrict__ x, const float* __restrict__ W,
               const float* __restrict__ bias, const float* __restrict__ gamma,
               const float* __restrict__ beta, const float* __restrict__ mean,
               const float* __restrict__ var,  const float* __restrict__ aP,
               YT* __restrict__ y, int P, int ptilesPerG, int bsx, int bsy)
{
    constexpr bool XF16 = (sizeof(XT) == 2);
    constexpr int NCO = COUT / 96;
    constexpr int NN  = (PT / 16) / 2;     // N-tiles per wave
    constexpr int LS  = XF16 ? 104 : 200;  // LDS row stride (f16 elems)
    extern __shared__ _Float16 ldsh[];
    _Float16* Xs = ldsh;                   // [PT][LS]; f32: 0-95 hi, 96-191 lo

    x += (size_t)blockIdx.y * bsx;
    y += (size_t)blockIdx.y * bsy;

    const int tid = threadIdx.x;
    const int pt  = blockIdx.x % ptilesPerG;
    const int cot = (blockIdx.x / ptilesPerG) % NCO;
    const int g   = blockIdx.x / (ptilesPerG * NCO);
    const int p0  = pt * PT;

    // ---- stage X: thread gathers 8 k for fixed p (loads lane-coalesced on p)
    const XT* xg = x + (size_t)g * 96 * P + p0;
    for (int e = tid; e < PT * 12; e += 256) {
        const int p = e % PT, k0 = (e / PT) * 8;
        const XT* xp = xg + (size_t)k0 * P + p;
        if constexpr (XF16) {
            h8 hv;
#pragma unroll
            for (int j = 0; j < 8; ++j) hv[j] = xp[(size_t)j * P];
            *(h8*)&Xs[p * LS + k0] = hv;
        } else {
            h8 hv, lv;
#pragma unroll
            for (int j = 0; j < 8; ++j) {
                const float xv = xp[(size_t)j * P];
                const _Float16 xh = (_Float16)xv;
                hv[j] = xh;
                lv[j] = (_Float16)(xv - (float)xh);
            }
            *(h8*)&Xs[p * LS + k0]      = hv;
            *(h8*)&Xs[p * LS + 96 + k0] = lv;
        }
    }

    const int lane = tid & 63, wid = tid >> 6;
    const int l16 = lane & 15, lg = lane >> 4;
    const int wm = wid >> 1, wn = wid & 1;       // 2x2 wave grid

    // ---- W A-frags from global (L2-resident), hi/lo split in-register ----
    const float* wg = W + (size_t)cot * 96 * 96;
    h8 af[3][6];
#pragma unroll
    for (int mt = 0; mt < 3; ++mt) {
        const float* wrow = wg + (size_t)((wm * 3 + mt) * 16 + l16) * 96 + lg * 8;
#pragma unroll
        for (int kk = 0; kk < 3; ++kk) {
            const f4 w0 = *(const f4*)(wrow + kk * 32);
            const f4 w1 = *(const f4*)(wrow + kk * 32 + 4);
#pragma unroll
            for (int j = 0; j < 4; ++j) {
                const _Float16 h0 = (_Float16)w0[j];
                const _Float16 h1 = (_Float16)w1[j];
                af[mt][kk][j]     = h0;
                af[mt][kk][4 + j] = h1;
                af[mt][kk + 3][j]     = (_Float16)(w0[j] - (float)h0);
                af[mt][kk + 3][4 + j] = (_Float16)(w1[j] - (float)h1);
            }
        }
    }
    __syncthreads();

    f32x4 acc[3][NN];
#pragma unroll
    for (int mt = 0; mt < 3; ++mt)
#pragma unroll
        for (int nn = 0; nn < NN; ++nn) acc[mt][nn] = (f32x4){0.f, 0.f, 0.f, 0.f};

    constexpr int XKMAX = XF16 ? 3 : 6;
#pragma unroll
    for (int xk = 0; xk < XKMAX; ++xk) {         // 0-2: Xh, 3-5: Xl (f32 only)
        h8 bf[NN];
#pragma unroll
        for (int nn = 0; nn < NN; ++nn)
            bf[nn] = *(const h8*)&Xs[((wn * NN + nn) * 16 + l16) * LS + xk * 32 + lg * 8];
        if (xk < 3) {
#pragma unroll
            for (int mt = 0; mt < 3; ++mt)
#pragma unroll
                for (int nn = 0; nn < NN; ++nn) {
                    acc[mt][nn] = __builtin_amdgcn_mfma_f32_16x16x32_f16(
                        af[mt][xk], bf[nn], acc[mt][nn], 0, 0, 0);       // xh*wh
                    acc[mt][nn] = __builtin_amdgcn_mfma_f32_16x16x32_f16(
                        af[mt][xk + 3], bf[nn], acc[mt][nn], 0, 0, 0);   // xh*wl
                }
        } else {
#pragma unroll
            for (int mt = 0; mt < 3; ++mt)
#pragma unroll
                for (int nn = 0; nn < NN; ++nn)
                    acc[mt][nn] = __builtin_amdgcn_mfma_f32_16x16x32_f16(
                        af[mt][xk - 3], bf[nn], acc[mt][nn], 0, 0, 0);   // xl*wh
        }
    }

    // ---- BN + PReLU epilogue (fp32), store YT ----
    const float a = aP[0];
    const int cobase = cot * 96;
#pragma unroll
    for (int mt = 0; mt < 3; ++mt) {
#pragma unroll
        for (int r = 0; r < 4; ++r) {
            const int co = cobase + (wm * 3 + mt) * 16 + lg * 4 + r;
            const float sc = gamma[co] * rsqrtf(var[co] + EPS_);
            const float sh = fmaf(bias[co] - mean[co], sc, beta[co]);
            YT* yr = y + ((size_t)g * COUT + co) * P + p0 + wn * NN * 16 + l16;
#pragma unroll
            for (int nn = 0; nn < NN; ++nn) {
                const float v = fmaf(acc[mt][nn][r], sc, sh);
                yr[nn * 16] = (YT)(v >= 0.f ? v : a * v);
            }
        }
    }
}

// ---------------------------------------------------------------------------
// f16 -> f16 2D transpose.  blockIdx.z = batch-in-pair (strides si/so).
// ---------------------------------------------------------------------------
__global__ __launch_bounds__(256)
void transpose_h(const _Float16* __restrict__ in, _Float16* __restrict__ out,
                 int Mo, int No, int si, int so)
{
    __shared__ _Float16 tile[32][34];
    in  += (size_t)blockIdx.z * si;
    out += (size_t)blockIdx.z * so;
    const int n0 = blockIdx.x * 32, m0 = blockIdx.y * 32;
    const int tx = threadIdx.x, ty = threadIdx.y;
#pragma unroll
    for (int i = 0; i < 32; i += 8)
        tile[ty + i][tx] = in[(size_t)(n0 + ty + i) * Mo + (m0 + tx)];
    __syncthreads();
#pragma unroll
    for (int i = 0; i < 32; i += 8)
        out[(size_t)(m0 + ty + i) * No + (n0 + tx)] = tile[tx][ty + i];
}

// ---------------------------------------------------------------------------
// f16 in + f32 residual -> f32 out transpose (final step).
// ---------------------------------------------------------------------------
__global__ __launch_bounds__(256)
void transpose_hf_res(const _Float16* __restrict__ in, const float* __restrict__ res,
                      float* __restrict__ out, int Mo, int No, int si, int sr, int so)
{
    __shared__ _Float16 tile[32][34];
    in  += (size_t)blockIdx.z * si;
    res += (size_t)blockIdx.z * sr;
    out += (size_t)blockIdx.z * so;
    const int n0 = blockIdx.x * 32, m0 = blockIdx.y * 32;
    const int tx = threadIdx.x, ty = threadIdx.y;
#pragma unroll
    for (int i = 0; i < 32; i += 8)
        tile[ty + i][tx] = in[(size_t)(n0 + ty + i) * Mo + (m0 + tx)];
    __syncthreads();
#pragma unroll
    for (int i = 0; i < 32; i += 8) {
        const size_t oidx = (size_t)(m0 + ty + i) * No + (n0 + tx);
        out[oidx] = (float)tile[tx][ty + i] + res[oidx];
    }
}

// ---------------------------------------------------------------------------
// MFMA f16 fused attention v3 — all-f16 I/O, pair-batched (blockIdx.y).
// S = softmax(Q^T K * scale); O = V P^T.
// MODE 0: groups t (320), NY=256, LD=TF_.  MODE 1: groups f (256), NY=320, LD=T_.
// Strip-major grid (XCD locality); Kt gather-8; per-wave P tiles; Q from global.
// ---------------------------------------------------------------------------
template<int MODE>
__global__ __launch_bounds__(256, 2)
void attn_mfma(const _Float16* __restrict__ Qb, const _Float16* __restrict__ Kb,
               const _Float16* __restrict__ Vb, _Float16* __restrict__ Ob,
               int qs, int ks, int vs, int os)
{
    constexpr int NY  = (MODE == 0) ? 256 : 320;
    constexpr int LD  = (MODE == 0) ? TF_ : T_;
    constexpr int NT  = NY / 16;
    constexpr int NYK = NY / 32;
    constexpr int KS  = 104;
    constexpr int VPS = NY + 24;
    constexpr int KVH = (NY * KS > 96 * VPS) ? NY * KS : 96 * VPS;
    constexpr int NG  = (MODE == 0) ? T_ : F_;
    constexpr int GOFF = (MODE == 0) ? F_ : C_ * T_;

    extern __shared__ _Float16 ldsh[];
    _Float16* KV = ldsh;                 // Kt[NY][KS] -> V[96][VPS]
    _Float16* Pw = ldsh + KVH;           // [4][16][40]

    const int lb    = blockIdx.y;
    const int strip = blockIdx.x / NG;
    const int grp   = blockIdx.x % NG;
    const int m0    = strip * 64;
    const size_t off = (size_t)grp * GOFF;
    const _Float16* Q = Qb + (size_t)lb * qs + off;
    const _Float16* K = Kb + (size_t)lb * ks + off;
    const _Float16* V = Vb + (size_t)lb * vs + off;
    _Float16*       O = Ob + (size_t)lb * os + off;

    const int tid  = threadIdx.x;
    const int lane = tid & 63, wid = tid >> 6;
    const int l16  = lane & 15, lg = lane >> 4;
    const int mw   = wid * 16;
    const float scale = 0.10206207261596575f;   // 1/sqrt(96)

    for (int e = tid; e < NY * 12; e += 256) {
        const int yy = e % NY, k0 = (e / NY) * 8;
        const _Float16* kp = K + (size_t)k0 * LD + yy;
        h8 hv;
#pragma unroll
        for (int j = 0; j < 8; ++j) hv[j] = kp[(size_t)j * LD];
        *(h8*)&KV[yy * KS + k0] = hv;
    }

    h8 aQ[3];
#pragma unroll
    for (int kk = 0; kk < 3; ++kk) {
        const _Float16* qp = Q + (size_t)(kk * 32 + lg * 8) * LD + m0 + mw + l16;
#pragma unroll
        for (int j = 0; j < 8; ++j) aQ[kk][j] = qp[(size_t)j * LD];
    }
    __syncthreads();

    f32x4 sacc[NT];
#pragma unroll
    for (int t = 0; t < NT; ++t) sacc[t] = (f32x4){0.f, 0.f, 0.f, 0.f};
#pragma unroll
    for (int kk = 0; kk < 3; ++kk) {
#pragma unroll
        for (int t = 0; t < NT; ++t) {
            const h8 bK = *(const h8*)&KV[(t * 16 + l16) * KS + kk * 32 + lg * 8];
            sacc[t] = __builtin_amdgcn_mfma_f32_16x16x32_f16(aQ[kk], bK, sacc[t], 0, 0, 0);
        }
    }

#pragma unroll
    for (int r = 0; r < 4; ++r) {
        float mx = sacc[0][r];
#pragma unroll
        for (int t = 1; t < NT; ++t) mx = fmaxf(mx, sacc[t][r]);
        for (int d = 1; d < 16; d <<= 1) mx = fmaxf(mx, __shfl_xor(mx, d));
        float pv[NT];
        float sum = 0.f;
#pragma unroll
        for (int t = 0; t < NT; ++t) {
            pv[t] = __expf((sacc[t][r] - mx) * scale); sum += pv[t];
        }
        for (int d = 1; d < 16; d <<= 1) sum += __shfl_xor(sum, d);
        const float inv = 1.f / sum;
#pragma unroll
        for (int t = 0; t < NT; ++t) sacc[t][r] = pv[t] * inv;
    }
    __syncthreads();

    constexpr int NY8 = NY / 8;
    for (int e = tid; e < 96 * NY8; e += 256) {
        const int c = e / NY8, y8 = e - c * NY8;
        *(h8*)&KV[c * VPS + y8 * 8] = *(const h8*)(V + (size_t)c * LD + y8 * 8);
    }
    __syncthreads();

    _Float16* Pme = Pw + wid * 640;      // [16][40]
    f32x4 oacc[6];
#pragma unroll
    for (int ct = 0; ct < 6; ++ct) oacc[ct] = (f32x4){0.f, 0.f, 0.f, 0.f};

#pragma unroll
    for (int yk = 0; yk < NYK; ++yk) {
#pragma unroll
        for (int h = 0; h < 2; ++h)
#pragma unroll
            for (int r = 0; r < 4; ++r)
                Pme[(lg * 4 + r) * 40 + h * 16 + l16] = (_Float16)sacc[2 * yk + h][r];
        const h8 pf = *(const h8*)&Pme[l16 * 40 + lg * 8];   // in-wave DS order
#pragma unroll
        for (int ct = 0; ct < 6; ++ct) {
            const h8 av = *(const h8*)&KV[(ct * 16 + l16) * VPS + yk * 32 + lg * 8];
            oacc[ct] = __builtin_amdgcn_mfma_f32_16x16x32_f16(av, pf, oacc[ct], 0, 0, 0);
        }
    }
#pragma unroll
    for (int ct = 0; ct < 6; ++ct)
#pragma unroll
        for (int r = 0; r < 4; ++r)
            O[(size_t)(ct * 16 + lg * 4 + r) * LD + m0 + mw + l16] = (_Float16)oacc[ct][r];
}

// ---------------------------------------------------------------------------
extern "C" void kernel_launch(void* const* d_in, const int* in_sizes, int n_in,
                              void* d_out, int out_size, void* d_ws, size_t ws_size,
                              hipStream_t stream)
{
    const float* inp = (const float*)d_in[0];
    const float* W_f = (const float*)d_in[1];  const float* b_f = (const float*)d_in[2];
    const float* g_f = (const float*)d_in[3];  const float* be_f = (const float*)d_in[4];
    const float* m_f = (const float*)d_in[5];  const float* v_f = (const float*)d_in[6];
    const float* a_f = (const float*)d_in[7];
    const float* W_t = (const float*)d_in[8];  const float* b_t = (const float*)d_in[9];
    const float* g_t = (const float*)d_in[10]; const float* be_t = (const float*)d_in[11];
    const float* m_t = (const float*)d_in[12]; const float* v_t = (const float*)d_in[13];
    const float* a_t = (const float*)d_in[14];
    const float* W_p = (const float*)d_in[15]; const float* b_p = (const float*)d_in[16];
    const float* g_p = (const float*)d_in[17]; const float* be_p = (const float*)d_in[18];
    const float* m_p = (const float*)d_in[19]; const float* v_p = (const float*)d_in[20];
    const float* a_p = (const float*)d_in[21];

    hipFuncSetAttribute((const void*)conv_mfma<float, _Float16, 288, 64, 3>,
                        hipFuncAttributeMaxDynamicSharedMemorySize, 25600);
    hipFuncSetAttribute((const void*)conv_mfma<float, _Float16, 192, 64, 3>,
                        hipFuncAttributeMaxDynamicSharedMemorySize, 25600);
    hipFuncSetAttribute((const void*)conv_mfma<_Float16, _Float16, 96, 160, 3>,
                        hipFuncAttributeMaxDynamicSharedMemorySize, 33280);
    hipFuncSetAttribute((const void*)attn_mfma<0>,
                        hipFuncAttributeMaxDynamicSharedMemorySize, 58880);
    hipFuncSetAttribute((const void*)attn_mfma<1>,
                        hipFuncAttributeMaxDynamicSharedMemorySize, 71680);

    // Pair-batched pipeline (G=2): 9 dispatches per pair, gridDim.y/z = 2.
    // ws (f16 units of QH elems): [0,6) = fqkv pair (stride 3);
    // after fqkv dies: foutT units 0,1 (stride 1); th2 units 2-5 (stride 2,
    // q at +0, k at +QH); tkT over dead q-halves (units 2,4); tout over dead
    // k-halves (units 3,5); tmp over dead foutT (units 0,1).
    // d_out pair slices hold fout -> tqT as f16 (stride 2*QH f16 elems).
    constexpr int QH = C_ * T_ * F_;            // 7,864,320 elems
    _Float16* wsh = (_Float16*)d_ws;

    for (int p = 0; p < 2; ++p) {
        const float* xb  = inp + (size_t)p * 2 * QH;
        float*       dob = (float*)d_out + (size_t)p * 2 * QH;
        _Float16*    doh = (_Float16*)dob;            // fout / tqT scratch
        _Float16* fqkv  = wsh;                        // stride 3*QH
        _Float16* foutT = wsh;                        // stride QH
        _Float16* th2   = wsh + (size_t)2 * QH;       // stride 2*QH (q,k halves)
        _Float16* tkT   = wsh + (size_t)2 * QH;       // stride 2*QH
        _Float16* tout  = wsh + (size_t)3 * QH;       // stride 2*QH
        _Float16* tmp   = wsh;                        // stride QH

        // 1. f_qkv = cbp_f(inp)                 (3C, T, F) f16
        conv_mfma<float, _Float16, 288, 64, 3><<<dim3(3 * 1280, 2), dim3(256), 25600, stream>>>(
            xb, W_f, b_f, g_f, be_f, m_f, v_f, a_f, fqkv, TF_, 1280, QH, 3 * QH);
        // 2. f-attention -> fout (d_out f16)    (C, T, F)
        attn_mfma<0><<<dim3(T_ * (F_ / 64), 2), dim3(256), 58880, stream>>>(
            fqkv, fqkv + (size_t)C_ * TF_, fqkv + (size_t)2 * C_ * TF_, doh,
            3 * QH, 3 * QH, 3 * QH, 2 * QH);
        // 3. foutT = transpose(fout)            (F, C, T) f16
        transpose_h<<<dim3(960, 8, 2), dim3(32, 8), 0, stream>>>(
            doh, foutT, F_, C_ * T_, 2 * QH, QH);
        // 4. th2 = cbp_t(inp)                   (2C, T, F) f16
        conv_mfma<float, _Float16, 192, 64, 3><<<dim3(2 * 1280, 2), dim3(256), 25600, stream>>>(
            xb, W_t, b_t, g_t, be_t, m_t, v_t, a_t, th2, TF_, 1280, QH, 2 * QH);
        // 5. tqT = transpose(th2 q-half) -> d_out f16 (fout dead)
        transpose_h<<<dim3(960, 8, 2), dim3(32, 8), 0, stream>>>(
            th2, doh, F_, C_ * T_, 2 * QH, 2 * QH);
        // 6. tkT = transpose(th2 k-half) -> units 2,4 (q-halves dead)
        transpose_h<<<dim3(960, 8, 2), dim3(32, 8), 0, stream>>>(
            th2 + (size_t)QH, tkT, F_, C_ * T_, 2 * QH, 2 * QH);
        // 7. t-attention(Q=tqT,K=tkT,V=foutT) -> tout units 3,5 (k-halves dead)
        attn_mfma<1><<<dim3(F_ * (T_ / 64), 2), dim3(256), 71680, stream>>>(
            doh, tkT, foutT, tout, 2 * QH, 2 * QH, QH, 2 * QH);
        // 8. tmp = cbp_p(tout) -> units 0,1 (foutT dead)   (F, C, T) f16
        conv_mfma<_Float16, _Float16, 96, 160, 3><<<dim3(256 * 2, 2), dim3(256), 33280, stream>>>(
            tout, W_p, b_p, g_p, be_p, m_p, v_p, a_p, tmp, T_, 2, 2 * QH, QH);
        // 9. out = transpose(tmp) + inp         (C, T, F) f32 (tqT dead)
        transpose_hf_res<<<dim3(8, 960, 2), dim3(32, 8), 0, stream>>>(
            tmp, xb, dob, C_ * T_, F_, QH, QH, QH);
    }
}

// Round 11
// 720.253 us; speedup vs baseline: 51.8040x; 1.1852x over previous
//
#include <hip/hip_runtime.h>
#include <math.h>

typedef float f4 __attribute__((ext_vector_type(4)));
typedef float f2 __attribute__((ext_vector_type(2)));
typedef float f32x4 __attribute__((ext_vector_type(4)));
typedef _Float16 h8 __attribute__((ext_vector_type(8)));

constexpr int B_ = 4, C_ = 96, T_ = 320, F_ = 256;
constexpr int TF_ = T_ * F_;          // 81920
constexpr float EPS_ = 1e-5f;
constexpr size_t QH_ = (size_t)C_ * TF_;   // 7,864,320 elems per (C,T,F) unit

// W-split scratch layout (f16 elems, at wsh + 6*QH_):
//   WhF 0  WlF 27648  WhT 55296  WlT 73728  WhP 92160  WlP 101376  (110592 tot)
// scsh (f32, after that): F 0..575, T 576..959, P 960..1151
constexpr int WHF = 0, WLF = 27648, WHT = 55296, WLT = 73728,
              WHP = 92160, WLP = 101376, WTOT = 110592;

// ---------------------------------------------------------------------------
// One-time prep: split W into hi/lo f16; precompute BN (sc, sh) per channel.
// ---------------------------------------------------------------------------
__global__ __launch_bounds__(256)
void prep_kernel(const float* __restrict__ Wf, const float* __restrict__ Wt,
                 const float* __restrict__ Wp,
                 const float* __restrict__ bf, const float* __restrict__ gf,
                 const float* __restrict__ bef, const float* __restrict__ mf,
                 const float* __restrict__ vf,
                 const float* __restrict__ bt, const float* __restrict__ gt,
                 const float* __restrict__ bet, const float* __restrict__ mt,
                 const float* __restrict__ vt,
                 const float* __restrict__ bp, const float* __restrict__ gp,
                 const float* __restrict__ bep, const float* __restrict__ mp,
                 const float* __restrict__ vp,
                 _Float16* __restrict__ wsp, float* __restrict__ scsh)
{
    const int gtid = blockIdx.x * 256 + threadIdx.x;
    const int gsz  = gridDim.x * 256;
    for (int i = gtid; i < 27648; i += gsz) {
        const float w = Wf[i]; const _Float16 h = (_Float16)w;
        wsp[WHF + i] = h; wsp[WLF + i] = (_Float16)(w - (float)h);
    }
    for (int i = gtid; i < 18432; i += gsz) {
        const float w = Wt[i]; const _Float16 h = (_Float16)w;
        wsp[WHT + i] = h; wsp[WLT + i] = (_Float16)(w - (float)h);
    }
    for (int i = gtid; i < 9216; i += gsz) {
        const float w = Wp[i]; const _Float16 h = (_Float16)w;
        wsp[WHP + i] = h; wsp[WLP + i] = (_Float16)(w - (float)h);
    }
    if (gtid < 288) {
        const float sc = gf[gtid] * rsqrtf(vf[gtid] + EPS_);
        scsh[2 * gtid] = sc;
        scsh[2 * gtid + 1] = fmaf(bf[gtid] - mf[gtid], sc, bef[gtid]);
    } else if (gtid < 480) {
        const int i = gtid - 288;
        const float sc = gt[i] * rsqrtf(vt[i] + EPS_);
        scsh[576 + 2 * i] = sc;
        scsh[576 + 2 * i + 1] = fmaf(bt[i] - mt[i], sc, bet[i]);
    } else if (gtid < 576) {
        const int i = gtid - 480;
        const float sc = gp[i] * rsqrtf(vp[i] + EPS_);
        scsh[960 + 2 * i] = sc;
        scsh[960 + 2 * i + 1] = fmaf(bp[i] - mp[i], sc, bep[i]);
    }
}

// ---------------------------------------------------------------------------
// Fused conv_f + conv_t (fp32 input, f16 outputs), pair-batched (blockIdx.y).
// Stage X hi/lo once per 64-p tile; loop 5 output groups (3 -> yf, 2 -> yt).
// W pre-split (h8 loads from L2), BN coeffs precomputed.  Per group per kk:
// acc += wh*xh + wl*xh + wh*xl  (drop xl*wl; fp32-accurate).
// ---------------------------------------------------------------------------
__global__ __launch_bounds__(256, 3)
void conv_ft(const float* __restrict__ x, const _Float16* __restrict__ wsp,
             const float* __restrict__ scsh,
             const float* __restrict__ aPf, const float* __restrict__ aPt,
             _Float16* __restrict__ yf, _Float16* __restrict__ yt,
             int bsx, int bsyf, int bsyt)
{
    constexpr int LS = 200;
    extern __shared__ _Float16 ldsh[];
    _Float16* Xs = ldsh;                   // [64][200]: 0-95 hi, 96-191 lo

    x  += (size_t)blockIdx.y * bsx;
    yf += (size_t)blockIdx.y * bsyf;
    yt += (size_t)blockIdx.y * bsyt;

    const int tid = threadIdx.x;
    const int p0  = blockIdx.x * 64;

    // ---- stage X hi/lo: gather 8 k per p, lanes coalesced on p ----
    const float* xg = x + p0;
    for (int e = tid; e < 64 * 12; e += 256) {
        const int p = e & 63, k0 = (e >> 6) * 8;
        const float* xp = xg + (size_t)k0 * TF_ + p;
        h8 hv, lv;
#pragma unroll
        for (int j = 0; j < 8; ++j) {
            const float xv = xp[(size_t)j * TF_];
            const _Float16 xh = (_Float16)xv;
            hv[j] = xh;
            lv[j] = (_Float16)(xv - (float)xh);
        }
        *(h8*)&Xs[p * LS + k0]      = hv;
        *(h8*)&Xs[p * LS + 96 + k0] = lv;
    }

    const int lane = tid & 63, wid = tid >> 6;
    const int l16 = lane & 15, lg = lane >> 4;
    const int wm = wid >> 1, wn = wid & 1;       // 2x2 wave grid
    const float af_ = aPf[0], at_ = aPt[0];
    __syncthreads();

#pragma unroll 1
    for (int cg = 0; cg < 5; ++cg) {
        const _Float16 *Wh, *Wl; const float* ss; float a; _Float16* yo;
        if (cg < 3) {
            Wh = wsp + WHF + cg * 9216;  Wl = wsp + WLF + cg * 9216;
            ss = scsh + cg * 192;        a = af_;
            yo = yf + (size_t)cg * QH_;
        } else {
            const int c2 = cg - 3;
            Wh = wsp + WHT + c2 * 9216;  Wl = wsp + WLT + c2 * 9216;
            ss = scsh + 576 + c2 * 192;  a = at_;
            yo = yt + (size_t)c2 * QH_;
        }

        f32x4 acc[3][2];
#pragma unroll
        for (int m = 0; m < 3; ++m)
#pragma unroll
            for (int n = 0; n < 2; ++n) acc[m][n] = (f32x4){0.f, 0.f, 0.f, 0.f};

#pragma unroll
        for (int kk = 0; kk < 3; ++kk) {
            h8 bfh[2], bfl[2];
#pragma unroll
            for (int n = 0; n < 2; ++n) {
                const int prow = (wn * 2 + n) * 16 + l16;
                bfh[n] = *(const h8*)&Xs[prow * LS + kk * 32 + lg * 8];
                bfl[n] = *(const h8*)&Xs[prow * LS + 96 + kk * 32 + lg * 8];
            }
#pragma unroll
            for (int m = 0; m < 3; ++m) {
                const int row = (wm * 3 + m) * 16 + l16;
                const h8 wh = *(const h8*)&Wh[row * 96 + kk * 32 + lg * 8];
                const h8 wl = *(const h8*)&Wl[row * 96 + kk * 32 + lg * 8];
#pragma unroll
                for (int n = 0; n < 2; ++n) {
                    acc[m][n] = __builtin_amdgcn_mfma_f32_16x16x32_f16(wh, bfh[n], acc[m][n], 0, 0, 0);
                    acc[m][n] = __builtin_amdgcn_mfma_f32_16x16x32_f16(wl, bfh[n], acc[m][n], 0, 0, 0);
                    acc[m][n] = __builtin_amdgcn_mfma_f32_16x16x32_f16(wh, bfl[n], acc[m][n], 0, 0, 0);
                }
            }
        }

#pragma unroll
        for (int m = 0; m < 3; ++m) {
#pragma unroll
            for (int r = 0; r < 4; ++r) {
                const int col = (wm * 3 + m) * 16 + lg * 4 + r;
                const f2 sp = *(const f2*)&ss[2 * col];
                _Float16* yr = yo + (size_t)col * TF_ + p0 + wn * 32 + l16;
#pragma unroll
                for (int n = 0; n < 2; ++n) {
                    const float v = fmaf(acc[m][n][r], sp[0], sp[1]);
                    yr[n * 16] = (_Float16)(v >= 0.f ? v : a * v);
                }
            }
        }
    }
}

// ---------------------------------------------------------------------------
// conv_p: f16 input (F groups, C, T), pre-split W, 160-p tiles, pair-batched.
// acc += wh*xh + wl*xh.
// ---------------------------------------------------------------------------
__global__ __launch_bounds__(256, 3)
void conv_p(const _Float16* __restrict__ x, const _Float16* __restrict__ wsp,
            const float* __restrict__ scsh, const float* __restrict__ aPp,
            _Float16* __restrict__ y, int bsx, int bsy)
{
    constexpr int LS = 104, PT = 160, NN = 5;
    extern __shared__ _Float16 ldsh[];
    _Float16* Xs = ldsh;                   // [160][104]

    x += (size_t)blockIdx.y * bsx;
    y += (size_t)blockIdx.y * bsy;

    const int tid = threadIdx.x;
    const int pt  = blockIdx.x & 1;
    const int g   = blockIdx.x >> 1;
    const int p0  = pt * PT;

    const _Float16* xg = x + (size_t)g * 96 * T_ + p0;
    for (int e = tid; e < PT * 12; e += 256) {
        const int p = e % PT, k0 = (e / PT) * 8;
        const _Float16* xp = xg + (size_t)k0 * T_ + p;
        h8 hv;
#pragma unroll
        for (int j = 0; j < 8; ++j) hv[j] = xp[(size_t)j * T_];
        *(h8*)&Xs[p * LS + k0] = hv;
    }

    const int lane = tid & 63, wid = tid >> 6;
    const int l16 = lane & 15, lg = lane >> 4;
    const int wm = wid >> 1, wn = wid & 1;
    const float a = aPp[0];
    const _Float16* Wh = wsp + WHP;
    const _Float16* Wl = wsp + WLP;
    const float* ss = scsh + 960;
    __syncthreads();

    f32x4 acc[3][NN];
#pragma unroll
    for (int m = 0; m < 3; ++m)
#pragma unroll
        for (int n = 0; n < NN; ++n) acc[m][n] = (f32x4){0.f, 0.f, 0.f, 0.f};

#pragma unroll
    for (int kk = 0; kk < 3; ++kk) {
        h8 bf[NN];
#pragma unroll
        for (int n = 0; n < NN; ++n)
            bf[n] = *(const h8*)&Xs[((wn * NN + n) * 16 + l16) * LS + kk * 32 + lg * 8];
#pragma unroll
        for (int m = 0; m < 3; ++m) {
            const int row = (wm * 3 + m) * 16 + l16;
            const h8 wh = *(const h8*)&Wh[row * 96 + kk * 32 + lg * 8];
            const h8 wl = *(const h8*)&Wl[row * 96 + kk * 32 + lg * 8];
#pragma unroll
            for (int n = 0; n < NN; ++n) {
                acc[m][n] = __builtin_amdgcn_mfma_f32_16x16x32_f16(wh, bf[n], acc[m][n], 0, 0, 0);
                acc[m][n] = __builtin_amdgcn_mfma_f32_16x16x32_f16(wl, bf[n], acc[m][n], 0, 0, 0);
            }
        }
    }

#pragma unroll
    for (int m = 0; m < 3; ++m) {
#pragma unroll
        for (int r = 0; r < 4; ++r) {
            const int col = (wm * 3 + m) * 16 + lg * 4 + r;
            const f2 sp = *(const f2*)&ss[2 * col];
            _Float16* yr = y + ((size_t)g * 96 + col) * T_ + p0 + wn * NN * 16 + l16;
#pragma unroll
            for (int n = 0; n < NN; ++n) {
                const float v = fmaf(acc[m][n][r], sp[0], sp[1]);
                yr[n * 16] = (_Float16)(v >= 0.f ? v : a * v);
            }
        }
    }
}

// ---------------------------------------------------------------------------
// f16 -> f16 2D transpose.  blockIdx.z = batch-in-pair (strides si/so).
// ---------------------------------------------------------------------------
__global__ __launch_bounds__(256)
void transpose_h(const _Float16* __restrict__ in, _Float16* __restrict__ out,
                 int Mo, int No, int si, int so)
{
    __shared__ _Float16 tile[32][34];
    in  += (size_t)blockIdx.z * si;
    out += (size_t)blockIdx.z * so;
    const int n0 = blockIdx.x * 32, m0 = blockIdx.y * 32;
    const int tx = threadIdx.x, ty = threadIdx.y;
#pragma unroll
    for (int i = 0; i < 32; i += 8)
        tile[ty + i][tx] = in[(size_t)(n0 + ty + i) * Mo + (m0 + tx)];
    __syncthreads();
#pragma unroll
    for (int i = 0; i < 32; i += 8)
        out[(size_t)(m0 + ty + i) * No + (n0 + tx)] = tile[tx][ty + i];
}

// ---------------------------------------------------------------------------
// f16 in + f32 residual -> f32 out transpose (final step).
// ---------------------------------------------------------------------------
__global__ __launch_bounds__(256)
void transpose_hf_res(const _Float16* __restrict__ in, const float* __restrict__ res,
                      float* __restrict__ out, int Mo, int No, int si, int sr, int so)
{
    __shared__ _Float16 tile[32][34];
    in  += (size_t)blockIdx.z * si;
    res += (size_t)blockIdx.z * sr;
    out += (size_t)blockIdx.z * so;
    const int n0 = blockIdx.x * 32, m0 = blockIdx.y * 32;
    const int tx = threadIdx.x, ty = threadIdx.y;
#pragma unroll
    for (int i = 0; i < 32; i += 8)
        tile[ty + i][tx] = in[(size_t)(n0 + ty + i) * Mo + (m0 + tx)];
    __syncthreads();
#pragma unroll
    for (int i = 0; i < 32; i += 8) {
        const size_t oidx = (size_t)(m0 + ty + i) * No + (n0 + tx);
        out[oidx] = (float)tile[tx][ty + i] + res[oidx];
    }
}

// ---------------------------------------------------------------------------
// MFMA f16 fused attention — all-f16 I/O, pair-batched.  O may alias Q
// (in-place): cell (c,grp,m) is read only by the block that writes it, and
// all its Q reads complete before its O writes.
// ---------------------------------------------------------------------------
template<int MODE>
__global__ __launch_bounds__(256, 2)
void attn_mfma(const _Float16* __restrict__ Qb, const _Float16* __restrict__ Kb,
               const _Float16* __restrict__ Vb, _Float16* __restrict__ Ob,
               int qs, int ks, int vs, int os)
{
    constexpr int NY  = (MODE == 0) ? 256 : 320;
    constexpr int LD  = (MODE == 0) ? TF_ : T_;
    constexpr int NT  = NY / 16;
    constexpr int NYK = NY / 32;
    constexpr int KS  = 104;
    constexpr int VPS = NY + 24;
    constexpr int KVH = (NY * KS > 96 * VPS) ? NY * KS : 96 * VPS;
    constexpr int NG  = (MODE == 0) ? T_ : F_;
    constexpr int GOFF = (MODE == 0) ? F_ : C_ * T_;

    extern __shared__ _Float16 ldsh[];
    _Float16* KV = ldsh;                 // Kt[NY][KS] -> V[96][VPS]
    _Float16* Pw = ldsh + KVH;           // [4][16][40]

    const int lb    = blockIdx.y;
    const int strip = blockIdx.x / NG;
    const int grp   = blockIdx.x % NG;
    const int m0    = strip * 64;
    const size_t off = (size_t)grp * GOFF;
    const _Float16* Q = Qb + (size_t)lb * qs + off;
    const _Float16* K = Kb + (size_t)lb * ks + off;
    const _Float16* V = Vb + (size_t)lb * vs + off;
    _Float16*       O = Ob + (size_t)lb * os + off;

    const int tid  = threadIdx.x;
    const int lane = tid & 63, wid = tid >> 6;
    const int l16  = lane & 15, lg = lane >> 4;
    const int mw   = wid * 16;
    const float scale = 0.10206207261596575f;   // 1/sqrt(96)

    for (int e = tid; e < NY * 12; e += 256) {
        const int yy = e % NY, k0 = (e / NY) * 8;
        const _Float16* kp = K + (size_t)k0 * LD + yy;
        h8 hv;
#pragma unroll
        for (int j = 0; j < 8; ++j) hv[j] = kp[(size_t)j * LD];
        *(h8*)&KV[yy * KS + k0] = hv;
    }

    h8 aQ[3];
#pragma unroll
    for (int kk = 0; kk < 3; ++kk) {
        const _Float16* qp = Q + (size_t)(kk * 32 + lg * 8) * LD + m0 + mw + l16;
#pragma unroll
        for (int j = 0; j < 8; ++j) aQ[kk][j] = qp[(size_t)j * LD];
    }
    __syncthreads();

    f32x4 sacc[NT];
#pragma unroll
    for (int t = 0; t < NT; ++t) sacc[t] = (f32x4){0.f, 0.f, 0.f, 0.f};
#pragma unroll
    for (int kk = 0; kk < 3; ++kk) {
#pragma unroll
        for (int t = 0; t < NT; ++t) {
            const h8 bK = *(const h8*)&KV[(t * 16 + l16) * KS + kk * 32 + lg * 8];
            sacc[t] = __builtin_amdgcn_mfma_f32_16x16x32_f16(aQ[kk], bK, sacc[t], 0, 0, 0);
        }
    }

#pragma unroll
    for (int r = 0; r < 4; ++r) {
        float mx = sacc[0][r];
#pragma unroll
        for (int t = 1; t < NT; ++t) mx = fmaxf(mx, sacc[t][r]);
        for (int d = 1; d < 16; d <<= 1) mx = fmaxf(mx, __shfl_xor(mx, d));
        float pv[NT];
        float sum = 0.f;
#pragma unroll
        for (int t = 0; t < NT; ++t) {
            pv[t] = __expf((sacc[t][r] - mx) * scale); sum += pv[t];
        }
        for (int d = 1; d < 16; d <<= 1) sum += __shfl_xor(sum, d);
        const float inv = 1.f / sum;
#pragma unroll
        for (int t = 0; t < NT; ++t) sacc[t][r] = pv[t] * inv;
    }
    __syncthreads();

    constexpr int NY8 = NY / 8;
    for (int e = tid; e < 96 * NY8; e += 256) {
        const int c = e / NY8, y8 = e - c * NY8;
        *(h8*)&KV[c * VPS + y8 * 8] = *(const h8*)(V + (size_t)c * LD + y8 * 8);
    }
    __syncthreads();

    _Float16* Pme = Pw + wid * 640;      // [16][40]
    f32x4 oacc[6];
#pragma unroll
    for (int ct = 0; ct < 6; ++ct) oacc[ct] = (f32x4){0.f, 0.f, 0.f, 0.f};

#pragma unroll
    for (int yk = 0; yk < NYK; ++yk) {
#pragma unroll
        for (int h = 0; h < 2; ++h)
#pragma unroll
            for (int r = 0; r < 4; ++r)
                Pme[(lg * 4 + r) * 40 + h * 16 + l16] = (_Float16)sacc[2 * yk + h][r];
        const h8 pf = *(const h8*)&Pme[l16 * 40 + lg * 8];   // in-wave DS order
#pragma unroll
        for (int ct = 0; ct < 6; ++ct) {
            const h8 av = *(const h8*)&KV[(ct * 16 + l16) * VPS + yk * 32 + lg * 8];
            oacc[ct] = __builtin_amdgcn_mfma_f32_16x16x32_f16(av, pf, oacc[ct], 0, 0, 0);
        }
    }
#pragma unroll
    for (int ct = 0; ct < 6; ++ct)
#pragma unroll
        for (int r = 0; r < 4; ++r)
            O[(size_t)(ct * 16 + lg * 4 + r) * LD + m0 + mw + l16] = (_Float16)oacc[ct][r];
}

// ---------------------------------------------------------------------------
extern "C" void kernel_launch(void* const* d_in, const int* in_sizes, int n_in,
                              void* d_out, int out_size, void* d_ws, size_t ws_size,
                              hipStream_t stream)
{
    const float* inp = (const float*)d_in[0];
    const float* W_f = (const float*)d_in[1];  const float* b_f = (const float*)d_in[2];
    const float* g_f = (const float*)d_in[3];  const float* be_f = (const float*)d_in[4];
    const float* m_f = (const float*)d_in[5];  const float* v_f = (const float*)d_in[6];
    const float* a_f = (const float*)d_in[7];
    const float* W_t = (const float*)d_in[8];  const float* b_t = (const float*)d_in[9];
    const float* g_t = (const float*)d_in[10]; const float* be_t = (const float*)d_in[11];
    const float* m_t = (const float*)d_in[12]; const float* v_t = (const float*)d_in[13];
    const float* a_t = (const float*)d_in[14];
    const float* W_p = (const float*)d_in[15]; const float* b_p = (const float*)d_in[16];
    const float* g_p = (const float*)d_in[17]; const float* be_p = (const float*)d_in[18];
    const float* m_p = (const float*)d_in[19]; const float* v_p = (const float*)d_in[20];
    const float* a_p = (const float*)d_in[21];

    hipFuncSetAttribute((const void*)conv_ft,
                        hipFuncAttributeMaxDynamicSharedMemorySize, 25600);
    hipFuncSetAttribute((const void*)conv_p,
                        hipFuncAttributeMaxDynamicSharedMemorySize, 33280);
    hipFuncSetAttribute((const void*)attn_mfma<0>,
                        hipFuncAttributeMaxDynamicSharedMemorySize, 58880);
    hipFuncSetAttribute((const void*)attn_mfma<1>,
                        hipFuncAttributeMaxDynamicSharedMemorySize, 71680);

    // ws: 6 f16 units of QH_ (fqkv pair; thirds recycled) + W/BN tail (226 KB).
    // d_out pair slice holds th2 (4 f16 units).  In-place O-over-Q in attns.
    constexpr int QH = (int)QH_;
    _Float16* wsh  = (_Float16*)d_ws;
    _Float16* wsp  = wsh + (size_t)6 * QH;           // W-split tail
    float*    scsh = (float*)(wsh + (size_t)6 * QH + WTOT);

    prep_kernel<<<dim3(128), dim3(256), 0, stream>>>(
        W_f, W_t, W_p, b_f, g_f, be_f, m_f, v_f,
        b_t, g_t, be_t, m_t, v_t, b_p, g_p, be_p, m_p, v_p, wsp, scsh);

    for (int p = 0; p < 2; ++p) {
        const float* xb  = inp + (size_t)p * 2 * QH;
        float*       dob = (float*)d_out + (size_t)p * 2 * QH;
        _Float16*    doh = (_Float16*)dob;           // th2 (4 units, stride 2QH)
        _Float16* fqkv  = wsh;                       // units 0-5, stride 3QH
        _Float16* foutT = wsh + QH;                  // units 1,4  stride 3QH
        _Float16* tqT   = wsh;                       // units 0,3  (fout dead)
        _Float16* tkT   = wsh + (size_t)2 * QH;      // units 2,5
        _Float16* tout  = wsh;                       // units 0,3  (over tqT)
        _Float16* tmp   = wsh + (size_t)2 * QH;      // units 2,5  (tkT dead)

        // 1. fused conv_f + conv_t: fqkv -> ws, th2 -> d_out slice (f16)
        conv_ft<<<dim3(1280, 2), dim3(256), 25600, stream>>>(
            xb, wsp, scsh, a_f, a_t, fqkv, doh, QH, 3 * QH, 2 * QH);
        // 2. f-attention, O in-place over Q third of fqkv
        attn_mfma<0><<<dim3(T_ * (F_ / 64), 2), dim3(256), 58880, stream>>>(
            fqkv, fqkv + QH_, fqkv + 2 * QH_, fqkv, 3 * QH, 3 * QH, 3 * QH, 3 * QH);
        // 3. foutT = transpose(fout) -> units 1,4 (K third dead)
        transpose_h<<<dim3(960, 8, 2), dim3(32, 8), 0, stream>>>(
            fqkv, foutT, F_, C_ * T_, 3 * QH, 3 * QH);
        // 4. tqT = transpose(th2 q-half) -> units 0,3 (fout dead)
        transpose_h<<<dim3(960, 8, 2), dim3(32, 8), 0, stream>>>(
            doh, tqT, F_, C_ * T_, 2 * QH, 3 * QH);
        // 5. tkT = transpose(th2 k-half) -> units 2,5 (V third dead)
        transpose_h<<<dim3(960, 8, 2), dim3(32, 8), 0, stream>>>(
            doh + QH_, tkT, F_, C_ * T_, 2 * QH, 3 * QH);
        // 6. t-attention, O in-place over tqT (units 0,3)
        attn_mfma<1><<<dim3(F_ * (T_ / 64), 2), dim3(256), 71680, stream>>>(
            tqT, tkT, foutT, tqT, 3 * QH, 3 * QH, 3 * QH, 3 * QH);
        // 7. conv_p(tout) -> tmp units 2,5 (tkT dead)
        conv_p<<<dim3(F_ * 2, 2), dim3(256), 33280, stream>>>(
            tout, wsp, scsh, a_p, tmp, 3 * QH, 3 * QH);
        // 8. out = transpose(tmp) + inp (th2 dead)
        transpose_hf_res<<<dim3(8, 960, 2), dim3(32, 8), 0, stream>>>(
            tmp, xb, dob, C_ * T_, F_, 3 * QH, QH, QH);
    }
}